// Round 6
// baseline (560.613 us; speedup 1.0000x reference)
//
#include <hip/hip_runtime.h>
#include <math.h>

// ---------------- histogram + in-bucket rank (the ONLY heavy atomic pass) ----------------
__global__ void hist_rank_kernel(const int* __restrict__ dst, int* __restrict__ cnt,
                                 int* __restrict__ rank, int E) {
    int t = blockIdx.x * blockDim.x + threadIdx.x;
    if (t < E) rank[t] = atomicAdd(&cnt[dst[t]], 1);
}

// exclusive scan, stage 1
__global__ __launch_bounds__(256) void scan_block(const int* __restrict__ in, int* __restrict__ out,
                                                  int* __restrict__ bsum, int n) {
    __shared__ int s[256];
    int tid = threadIdx.x;
    int base = blockIdx.x * 1024 + tid * 4;
    int a0 = (base + 0 < n) ? in[base + 0] : 0;
    int a1 = (base + 1 < n) ? in[base + 1] : 0;
    int a2 = (base + 2 < n) ? in[base + 2] : 0;
    int a3 = (base + 3 < n) ? in[base + 3] : 0;
    int tsum = a0 + a1 + a2 + a3;
    s[tid] = tsum;
    __syncthreads();
    for (int off = 1; off < 256; off <<= 1) {
        int v = (tid >= off) ? s[tid - off] : 0;
        __syncthreads();
        s[tid] += v;
        __syncthreads();
    }
    int texcl = s[tid] - tsum;
    if (base + 0 < n) out[base + 0] = texcl;
    if (base + 1 < n) out[base + 1] = texcl + a0;
    if (base + 2 < n) out[base + 2] = texcl + a0 + a1;
    if (base + 3 < n) out[base + 3] = texcl + a0 + a1 + a2;
    if (tid == 255) bsum[blockIdx.x] = s[255];
}

// stage 2: exclusive scan of block sums
__global__ __launch_bounds__(256) void scan_bsums(int* __restrict__ bsum, int nb) {
    __shared__ int s[256];
    __shared__ int carry_s;
    int tid = threadIdx.x;
    if (tid == 0) carry_s = 0;
    __syncthreads();
    for (int base = 0; base < nb; base += 256) {
        int v = (base + tid < nb) ? bsum[base + tid] : 0;
        int orig = v;
        s[tid] = v;
        __syncthreads();
        for (int off = 1; off < 256; off <<= 1) {
            int u = (tid >= off) ? s[tid - off] : 0;
            __syncthreads();
            s[tid] += u;
            __syncthreads();
        }
        int carry = carry_s;
        int excl = s[tid] - orig + carry;
        if (base + tid < nb) bsum[base + tid] = excl;
        int tot = s[255];
        __syncthreads();
        if (tid == 0) carry_s = carry + tot;
        __syncthreads();
    }
}

// stage 3: add block offsets
__global__ void scan_add(int* __restrict__ rowptr, const int* __restrict__ bscan, int n) {
    int t = blockIdx.x * blockDim.x + threadIdx.x;
    if (t < n) rowptr[t] += bscan[t >> 10];
}

// atomic-free CSR placement: pairs[rowptr[d] + rank[e]] = (src, ew)
__global__ void scatter_pairs(const int* __restrict__ src, const int* __restrict__ dst,
                              const float* __restrict__ ew, const int* __restrict__ rowptr,
                              const int* __restrict__ rank, int2* __restrict__ pairs, int E) {
    int e = blockIdx.x * blockDim.x + threadIdx.x;
    if (e >= E) return;
    int d = dst[e];
    int p = rowptr[d] + rank[e];
    pairs[p] = make_int2(src[e], __float_as_int(ew[e]));
}

// degree from sequential segment sum of sorted ew; dinv = 1/sqrt(deg+1)
__global__ void deg_dinv_kernel(const int2* __restrict__ pairs, const int* __restrict__ rowptr,
                                float* __restrict__ dinv, int n) {
    int i = blockIdx.x * blockDim.x + threadIdx.x;
    if (i >= n) return;
    int beg = rowptr[i], end = rowptr[i + 1];
    float s = 0.f;
    for (int j = beg; j < end; j++) s += __int_as_float(pairs[j].y);
    dinv[i] = 1.0f / sqrtf(s + 1.0f);   // self-loop weight folded in
}

// w' = dinv[src] * ew  (dinv[dst] factored out, applied in gather epilogue)
__global__ void norm_kernel(int2* __restrict__ pairs, const float* __restrict__ dinv, int E) {
    int j = blockIdx.x * blockDim.x + threadIdx.x;
    if (j >= E) return;
    int2 pr = pairs[j];
    pairs[j].y = __float_as_int(__int_as_float(pr.y) * dinv[pr.x]);
}

// ---------------- register-tiled GEMM: Y[n,OUT] = X[n,128] @ W[128,OUT] ----------------
// M=96 rows/block. X reads are row-broadcast across the col-group lanes -> no pad needed.
template<int OUT>
__global__ __launch_bounds__(256) void gemm_rt(const float* __restrict__ X,
                                               const float* __restrict__ W,
                                               float* __restrict__ Y, int n) {
    constexpr int CG  = OUT / 4;    // col-groups: 32 or 16
    constexpr int RG  = 256 / CG;   // row-groups: 8 or 16
    constexpr int M   = 96;
    constexpr int RT  = M / RG;     // rows/thread: 12 or 6
    constexpr int KC  = 32;
    __shared__ float4 Xl[M * 32];        // 49152 B
    __shared__ float4 Wl[KC * CG];       // 16384 B (OUT=128) / 8192 B

    int t = threadIdx.x;
    int row0 = blockIdx.x * M;

    {
        const float4* Xg = (const float4*)X;
        for (int f = t; f < M * 32; f += 256) {
            int r = f >> 5, c4 = f & 31;
            int gr = row0 + r;
            float4 v = make_float4(0.f, 0.f, 0.f, 0.f);
            if (gr < n) v = Xg[(size_t)gr * 32 + c4];
            Xl[f] = v;
        }
    }

    int cg = t % CG;
    int r0 = (t / CG) * RT;

    float4 acc[RT];
#pragma unroll
    for (int r = 0; r < RT; r++) acc[r] = make_float4(0.f, 0.f, 0.f, 0.f);

    const float4* Wg = (const float4*)W;
    for (int kc = 0; kc < 128; kc += KC) {
        __syncthreads();
        for (int f = t; f < KC * CG; f += 256)
            Wl[f] = Wg[(size_t)kc * CG + f];
        __syncthreads();
#pragma unroll 4
        for (int k = 0; k < KC; k += 4) {
            float4 b0 = Wl[(k + 0) * CG + cg];
            float4 b1 = Wl[(k + 1) * CG + cg];
            float4 b2 = Wl[(k + 2) * CG + cg];
            float4 b3 = Wl[(k + 3) * CG + cg];
#pragma unroll
            for (int r = 0; r < RT; r++) {
                float4 a = Xl[(r0 + r) * 32 + (kc + k) / 4];
                acc[r].x += a.x * b0.x + a.y * b1.x + a.z * b2.x + a.w * b3.x;
                acc[r].y += a.x * b0.y + a.y * b1.y + a.z * b2.y + a.w * b3.y;
                acc[r].z += a.x * b0.z + a.y * b1.z + a.z * b2.z + a.w * b3.z;
                acc[r].w += a.x * b0.w + a.y * b1.w + a.z * b2.w + a.w * b3.w;
            }
        }
    }

#pragma unroll
    for (int r = 0; r < RT; r++) {
        int gr = row0 + r0 + r;
        if (gr < n) *(float4*)&Y[(size_t)gr * OUT + cg * 4] = acc[r];
    }
}

// ---------------- CSR segmented gather-reduce, 8-deep explicit MLP ----------------
// out = di*(sum_j w'_j H[s_j] + di*H[node]) + bias,  w' = dinv[src]*ew
template<int C, bool RELU>
__global__ __launch_bounds__(256) void gather_reduce(const float* __restrict__ H,
                                                     const int* __restrict__ rowptr,
                                                     const int2* __restrict__ pairs,
                                                     const float* __restrict__ dinv,
                                                     const float* __restrict__ bias,
                                                     float* __restrict__ out, int n) {
    constexpr int TPN = C / 4;
    int t = blockIdx.x * blockDim.x + threadIdx.x;
    int node = t / TPN;
    int c4 = t % TPN;
    if (node >= n) return;
    const float4* H4 = (const float4*)H;
    int beg = rowptr[node], end = rowptr[node + 1];
    float di = dinv[node];
    float4 hv = H4[(size_t)node * TPN + c4];
    float4 bb = ((const float4*)bias)[c4];
    float4 a0, a1, a2, a3;
    a0.x = hv.x * di; a0.y = hv.y * di; a0.z = hv.z * di; a0.w = hv.w * di;
    a1 = make_float4(0.f, 0.f, 0.f, 0.f);
    a2 = make_float4(0.f, 0.f, 0.f, 0.f);
    a3 = make_float4(0.f, 0.f, 0.f, 0.f);
    int j = beg;
    // 8-wide: 8 pairs loads, then 8 independent H gathers in flight, then FMAs
    for (; j + 8 <= end; j += 8) {
        int2 p0 = pairs[j + 0], p1 = pairs[j + 1], p2 = pairs[j + 2], p3 = pairs[j + 3];
        int2 p4 = pairs[j + 4], p5 = pairs[j + 5], p6 = pairs[j + 6], p7 = pairs[j + 7];
        float4 v0 = H4[(size_t)p0.x * TPN + c4];
        float4 v1 = H4[(size_t)p1.x * TPN + c4];
        float4 v2 = H4[(size_t)p2.x * TPN + c4];
        float4 v3 = H4[(size_t)p3.x * TPN + c4];
        float4 v4 = H4[(size_t)p4.x * TPN + c4];
        float4 v5 = H4[(size_t)p5.x * TPN + c4];
        float4 v6 = H4[(size_t)p6.x * TPN + c4];
        float4 v7 = H4[(size_t)p7.x * TPN + c4];
        float w0 = __int_as_float(p0.y), w1 = __int_as_float(p1.y);
        float w2 = __int_as_float(p2.y), w3 = __int_as_float(p3.y);
        float w4 = __int_as_float(p4.y), w5 = __int_as_float(p5.y);
        float w6 = __int_as_float(p6.y), w7 = __int_as_float(p7.y);
        a0.x += v0.x * w0; a0.y += v0.y * w0; a0.z += v0.z * w0; a0.w += v0.w * w0;
        a1.x += v1.x * w1; a1.y += v1.y * w1; a1.z += v1.z * w1; a1.w += v1.w * w1;
        a2.x += v2.x * w2; a2.y += v2.y * w2; a2.z += v2.z * w2; a2.w += v2.w * w2;
        a3.x += v3.x * w3; a3.y += v3.y * w3; a3.z += v3.z * w3; a3.w += v3.w * w3;
        a0.x += v4.x * w4; a0.y += v4.y * w4; a0.z += v4.z * w4; a0.w += v4.w * w4;
        a1.x += v5.x * w5; a1.y += v5.y * w5; a1.z += v5.z * w5; a1.w += v5.w * w5;
        a2.x += v6.x * w6; a2.y += v6.y * w6; a2.z += v6.z * w6; a2.w += v6.w * w6;
        a3.x += v7.x * w7; a3.y += v7.y * w7; a3.z += v7.z * w7; a3.w += v7.w * w7;
    }
    if (j + 4 <= end) {
        int2 p0 = pairs[j + 0], p1 = pairs[j + 1], p2 = pairs[j + 2], p3 = pairs[j + 3];
        float4 v0 = H4[(size_t)p0.x * TPN + c4];
        float4 v1 = H4[(size_t)p1.x * TPN + c4];
        float4 v2 = H4[(size_t)p2.x * TPN + c4];
        float4 v3 = H4[(size_t)p3.x * TPN + c4];
        float w0 = __int_as_float(p0.y), w1 = __int_as_float(p1.y);
        float w2 = __int_as_float(p2.y), w3 = __int_as_float(p3.y);
        a0.x += v0.x * w0; a0.y += v0.y * w0; a0.z += v0.z * w0; a0.w += v0.w * w0;
        a1.x += v1.x * w1; a1.y += v1.y * w1; a1.z += v1.z * w1; a1.w += v1.w * w1;
        a2.x += v2.x * w2; a2.y += v2.y * w2; a2.z += v2.z * w2; a2.w += v2.w * w2;
        a3.x += v3.x * w3; a3.y += v3.y * w3; a3.z += v3.z * w3; a3.w += v3.w * w3;
        j += 4;
    }
    for (; j < end; j++) {
        int2 pr = pairs[j];
        float w = __int_as_float(pr.y);
        float4 v = H4[(size_t)pr.x * TPN + c4];
        a0.x += v.x * w; a0.y += v.y * w; a0.z += v.z * w; a0.w += v.w * w;
    }
    float4 acc;
    acc.x = ((a0.x + a1.x) + (a2.x + a3.x)) * di + bb.x;
    acc.y = ((a0.y + a1.y) + (a2.y + a3.y)) * di + bb.y;
    acc.z = ((a0.z + a1.z) + (a2.z + a3.z)) * di + bb.z;
    acc.w = ((a0.w + a1.w) + (a2.w + a3.w)) * di + bb.w;
    if (RELU) {
        acc.x = fmaxf(acc.x, 0.f);
        acc.y = fmaxf(acc.y, 0.f);
        acc.z = fmaxf(acc.z, 0.f);
        acc.w = fmaxf(acc.w, 0.f);
    }
    *(float4*)&out[(size_t)node * C + c4 * 4] = acc;
}

// ---------------- decode ----------------
__global__ void decode_kernel(const float* __restrict__ Z, const int* __restrict__ ea,
                              const int* __restrict__ eb, float* __restrict__ out, int L) {
    int t = blockIdx.x * blockDim.x + threadIdx.x;
    int e = t >> 4;
    int c = (t & 15) << 2;
    if (e >= L) return;
    float4 za = *(const float4*)&Z[(size_t)ea[e] * 64 + c];
    float4 zb = *(const float4*)&Z[(size_t)eb[e] * 64 + c];
    float p = za.x * zb.x + za.y * zb.y + za.z * zb.z + za.w * zb.w;
    p += __shfl_xor(p, 1);
    p += __shfl_xor(p, 2);
    p += __shfl_xor(p, 4);
    p += __shfl_xor(p, 8);
    if ((t & 15) == 0) out[e] = p;
}

extern "C" void kernel_launch(void* const* d_in, const int* in_sizes, int n_in,
                              void* d_out, int out_size, void* d_ws, size_t ws_size,
                              hipStream_t stream) {
    const float* x   = (const float*)d_in[0];
    const int*   ei  = (const int*)d_in[1];   // [2,E] flat: src = ei, dst = ei+E
    const float* ew  = (const float*)d_in[2];
    const int*   eli = (const int*)d_in[3];   // [2,L] flat
    const float* W1  = (const float*)d_in[4];
    const float* b1  = (const float*)d_in[5];
    const float* W2  = (const float*)d_in[6];
    const float* b2  = (const float*)d_in[7];
    float* out = (float*)d_out;

    const int N = in_sizes[0] / 128;
    const int E = in_sizes[2];
    const int L = in_sizes[3] / 2;
    const int NP = ((N + 255) / 256) * 256;

    float* ws     = (float*)d_ws;
    float* dinv   = ws;                                  // NP
    int*   cnt    = (int*)(ws + NP);                     // NP (needs N+1)
    int*   rowptr = cnt + NP;                            // NP (needs N+1)
    int*   bsum   = rowptr + NP;                         // 1024
    int*   rank   = bsum + 1024;                         // E
    int2*  pairs  = (int2*)(rank + E);                   // E int2
    float* A      = (float*)(pairs + E);                 // NP*128
    float* B      = A + (size_t)NP * 128;                // NP*128

    const int n1 = N + 1;
    const int nb = (n1 + 1023) / 1024;

    hipMemsetAsync(cnt, 0, (size_t)n1 * 4, stream);
    hist_rank_kernel<<<(E + 255) / 256, 256, 0, stream>>>(ei + E, cnt, rank, E);
    scan_block<<<nb, 256, 0, stream>>>(cnt, rowptr, bsum, n1);
    scan_bsums<<<1, 256, 0, stream>>>(bsum, nb);
    scan_add<<<(n1 + 255) / 256, 256, 0, stream>>>(rowptr, bsum, n1);
    scatter_pairs<<<(E + 255) / 256, 256, 0, stream>>>(ei, ei + E, ew, rowptr, rank, pairs, E);
    deg_dinv_kernel<<<(N + 255) / 256, 256, 0, stream>>>(pairs, rowptr, dinv, N);
    norm_kernel<<<(E + 255) / 256, 256, 0, stream>>>(pairs, dinv, E);

    // layer 1
    gemm_rt<128><<<(N + 95) / 96, 256, 0, stream>>>(x, W1, A, N);
    gather_reduce<128, true><<<(N * 32 + 255) / 256, 256, 0, stream>>>(A, rowptr, pairs, dinv, b1, B, N);

    // layer 2
    gemm_rt<64><<<(N + 95) / 96, 256, 0, stream>>>(B, W2, A, N);
    gather_reduce<64, false><<<(N * 16 + 255) / 256, 256, 0, stream>>>(A, rowptr, pairs, dinv, b2, B, N);

    // decode
    decode_kernel<<<(L * 16 + 255) / 256, 256, 0, stream>>>(B, eli, eli + L, out, L);
}

// Round 7
// 533.203 us; speedup vs baseline: 1.0514x; 1.0514x over previous
//
#include <hip/hip_runtime.h>
#include <math.h>

// ---------------- histogram + in-bucket rank (the ONLY heavy atomic pass) ----------------
__global__ void hist_rank_kernel(const int* __restrict__ dst, int* __restrict__ cnt,
                                 int* __restrict__ rank, int E) {
    int t = blockIdx.x * blockDim.x + threadIdx.x;
    if (t < E) rank[t] = atomicAdd(&cnt[dst[t]], 1);
}

// exclusive scan, stage 1
__global__ __launch_bounds__(256) void scan_block(const int* __restrict__ in, int* __restrict__ out,
                                                  int* __restrict__ bsum, int n) {
    __shared__ int s[256];
    int tid = threadIdx.x;
    int base = blockIdx.x * 1024 + tid * 4;
    int a0 = (base + 0 < n) ? in[base + 0] : 0;
    int a1 = (base + 1 < n) ? in[base + 1] : 0;
    int a2 = (base + 2 < n) ? in[base + 2] : 0;
    int a3 = (base + 3 < n) ? in[base + 3] : 0;
    int tsum = a0 + a1 + a2 + a3;
    s[tid] = tsum;
    __syncthreads();
    for (int off = 1; off < 256; off <<= 1) {
        int v = (tid >= off) ? s[tid - off] : 0;
        __syncthreads();
        s[tid] += v;
        __syncthreads();
    }
    int texcl = s[tid] - tsum;
    if (base + 0 < n) out[base + 0] = texcl;
    if (base + 1 < n) out[base + 1] = texcl + a0;
    if (base + 2 < n) out[base + 2] = texcl + a0 + a1;
    if (base + 3 < n) out[base + 3] = texcl + a0 + a1 + a2;
    if (tid == 255) bsum[blockIdx.x] = s[255];
}

// stage 2: exclusive scan of block sums
__global__ __launch_bounds__(256) void scan_bsums(int* __restrict__ bsum, int nb) {
    __shared__ int s[256];
    __shared__ int carry_s;
    int tid = threadIdx.x;
    if (tid == 0) carry_s = 0;
    __syncthreads();
    for (int base = 0; base < nb; base += 256) {
        int v = (base + tid < nb) ? bsum[base + tid] : 0;
        int orig = v;
        s[tid] = v;
        __syncthreads();
        for (int off = 1; off < 256; off <<= 1) {
            int u = (tid >= off) ? s[tid - off] : 0;
            __syncthreads();
            s[tid] += u;
            __syncthreads();
        }
        int carry = carry_s;
        int excl = s[tid] - orig + carry;
        if (base + tid < nb) bsum[base + tid] = excl;
        int tot = s[255];
        __syncthreads();
        if (tid == 0) carry_s = carry + tot;
        __syncthreads();
    }
}

// stage 3: add block offsets
__global__ void scan_add(int* __restrict__ rowptr, const int* __restrict__ bscan, int n) {
    int t = blockIdx.x * blockDim.x + threadIdx.x;
    if (t < n) rowptr[t] += bscan[t >> 10];
}

// atomic-free CSR placement: pairs[rowptr[d] + rank[e]] = (src, ew)
__global__ void scatter_pairs(const int* __restrict__ src, const int* __restrict__ dst,
                              const float* __restrict__ ew, const int* __restrict__ rowptr,
                              const int* __restrict__ rank, int2* __restrict__ pairs, int E) {
    int e = blockIdx.x * blockDim.x + threadIdx.x;
    if (e >= E) return;
    int d = dst[e];
    int p = rowptr[d] + rank[e];
    pairs[p] = make_int2(src[e], __float_as_int(ew[e]));
}

// degree from sequential segment sum of sorted ew; dinv = 1/sqrt(deg+1)
__global__ void deg_dinv_kernel(const int2* __restrict__ pairs, const int* __restrict__ rowptr,
                                float* __restrict__ dinv, int n) {
    int i = blockIdx.x * blockDim.x + threadIdx.x;
    if (i >= n) return;
    int beg = rowptr[i], end = rowptr[i + 1];
    float s = 0.f;
    for (int j = beg; j < end; j++) s += __int_as_float(pairs[j].y);
    dinv[i] = 1.0f / sqrtf(s + 1.0f);   // self-loop weight folded in
}

// w' = dinv[src] * ew  (dinv[dst] factored out, applied in gather epilogue)
__global__ void norm_kernel(int2* __restrict__ pairs, const float* __restrict__ dinv, int E) {
    int j = blockIdx.x * blockDim.x + threadIdx.x;
    if (j >= E) return;
    int2 pr = pairs[j];
    pairs[j].y = __float_as_int(__int_as_float(pr.y) * dinv[pr.x]);
}

// ---------------- register-tiled GEMM: Y[n,OUT] = X[n,128] @ W[128,OUT] ----------------
// M=64, LDS ~50KB -> 3 blocks/CU (M=96 regressed: 64KB LDS -> 2 blocks/CU)
template<int OUT>
__global__ __launch_bounds__(256) void gemm_rt(const float* __restrict__ X,
                                               const float* __restrict__ W,
                                               float* __restrict__ Y, int n) {
    constexpr int CG  = OUT / 4;
    constexpr int RG  = 256 / CG;
    constexpr int M   = 64;
    constexpr int RT  = M / RG;
    constexpr int KC  = 32;
    constexpr int LDX = 132;
    __shared__ float  Xl[M * LDX];
    __shared__ float4 Wl[KC * CG];

    int t = threadIdx.x;
    int row0 = blockIdx.x * M;

    {
        const float4* Xg = (const float4*)X;
        for (int f = t; f < M * 32; f += 256) {
            int r = f >> 5, c4 = f & 31;
            int gr = row0 + r;
            float4 v = make_float4(0.f, 0.f, 0.f, 0.f);
            if (gr < n) v = Xg[(size_t)gr * 32 + c4];
            *(float4*)&Xl[r * LDX + c4 * 4] = v;
        }
    }

    int cg = t % CG;
    int r0 = (t / CG) * RT;

    float4 acc[RT];
#pragma unroll
    for (int r = 0; r < RT; r++) acc[r] = make_float4(0.f, 0.f, 0.f, 0.f);

    const float4* Wg = (const float4*)W;
    for (int kc = 0; kc < 128; kc += KC) {
        __syncthreads();
        for (int f = t; f < KC * CG; f += 256)
            Wl[f] = Wg[(size_t)kc * CG + f];
        __syncthreads();
#pragma unroll 4
        for (int k = 0; k < KC; k += 4) {
            float4 b0 = Wl[(k + 0) * CG + cg];
            float4 b1 = Wl[(k + 1) * CG + cg];
            float4 b2 = Wl[(k + 2) * CG + cg];
            float4 b3 = Wl[(k + 3) * CG + cg];
#pragma unroll
            for (int r = 0; r < RT; r++) {
                float4 a = *(float4*)&Xl[(r0 + r) * LDX + kc + k];
                acc[r].x += a.x * b0.x + a.y * b1.x + a.z * b2.x + a.w * b3.x;
                acc[r].y += a.x * b0.y + a.y * b1.y + a.z * b2.y + a.w * b3.y;
                acc[r].z += a.x * b0.z + a.y * b1.z + a.z * b2.z + a.w * b3.z;
                acc[r].w += a.x * b0.w + a.y * b1.w + a.z * b2.w + a.w * b3.w;
            }
        }
    }

#pragma unroll
    for (int r = 0; r < RT; r++) {
        int gr = row0 + r0 + r;
        if (gr < n) *(float4*)&Y[(size_t)gr * OUT + cg * 4] = acc[r];
    }
}

// ---------------- CSR segmented gather-reduce, channel-split into PARTS passes ----------------
// Each pass covers C/PARTS channels -> serialized passes shrink the temporal H working set.
// out = di*(sum_j w'_j H[s_j] + di*H[node]) + bias,  w' = dinv[src]*ew
template<int C, int PARTS, bool RELU>
__global__ __launch_bounds__(256) void gather_reduce(const float* __restrict__ H,
                                                     const int* __restrict__ rowptr,
                                                     const int2* __restrict__ pairs,
                                                     const float* __restrict__ dinv,
                                                     const float* __restrict__ bias,
                                                     float* __restrict__ out, int n, int part) {
    constexpr int RS  = C / 4;            // float4s per row
    constexpr int TPN = RS / PARTS;       // threads per node in this pass
    int t = blockIdx.x * blockDim.x + threadIdx.x;
    int node = t / TPN;
    int c4 = part * TPN + (t % TPN);
    if (node >= n) return;
    const float4* H4 = (const float4*)H;
    int beg = rowptr[node], end = rowptr[node + 1];
    float di = dinv[node];
    float4 hv = H4[(size_t)node * RS + c4];
    float4 bb = ((const float4*)bias)[c4];
    float4 a0, a1, a2, a3;
    a0.x = hv.x * di; a0.y = hv.y * di; a0.z = hv.z * di; a0.w = hv.w * di;
    a1 = make_float4(0.f, 0.f, 0.f, 0.f);
    a2 = make_float4(0.f, 0.f, 0.f, 0.f);
    a3 = make_float4(0.f, 0.f, 0.f, 0.f);
    int j = beg;
    for (; j + 4 <= end; j += 4) {
        int2 p0 = pairs[j + 0], p1 = pairs[j + 1], p2 = pairs[j + 2], p3 = pairs[j + 3];
        float4 v0 = H4[(size_t)p0.x * RS + c4];
        float4 v1 = H4[(size_t)p1.x * RS + c4];
        float4 v2 = H4[(size_t)p2.x * RS + c4];
        float4 v3 = H4[(size_t)p3.x * RS + c4];
        float w0 = __int_as_float(p0.y), w1 = __int_as_float(p1.y);
        float w2 = __int_as_float(p2.y), w3 = __int_as_float(p3.y);
        a0.x += v0.x * w0; a0.y += v0.y * w0; a0.z += v0.z * w0; a0.w += v0.w * w0;
        a1.x += v1.x * w1; a1.y += v1.y * w1; a1.z += v1.z * w1; a1.w += v1.w * w1;
        a2.x += v2.x * w2; a2.y += v2.y * w2; a2.z += v2.z * w2; a2.w += v2.w * w2;
        a3.x += v3.x * w3; a3.y += v3.y * w3; a3.z += v3.z * w3; a3.w += v3.w * w3;
    }
    for (; j < end; j++) {
        int2 pr = pairs[j];
        float w = __int_as_float(pr.y);
        float4 v = H4[(size_t)pr.x * RS + c4];
        a0.x += v.x * w; a0.y += v.y * w; a0.z += v.z * w; a0.w += v.w * w;
    }
    float4 acc;
    acc.x = ((a0.x + a1.x) + (a2.x + a3.x)) * di + bb.x;
    acc.y = ((a0.y + a1.y) + (a2.y + a3.y)) * di + bb.y;
    acc.z = ((a0.z + a1.z) + (a2.z + a3.z)) * di + bb.z;
    acc.w = ((a0.w + a1.w) + (a2.w + a3.w)) * di + bb.w;
    if (RELU) {
        acc.x = fmaxf(acc.x, 0.f);
        acc.y = fmaxf(acc.y, 0.f);
        acc.z = fmaxf(acc.z, 0.f);
        acc.w = fmaxf(acc.w, 0.f);
    }
    *(float4*)&out[(size_t)node * C + c4 * 4] = acc;
}

// ---------------- decode ----------------
__global__ void decode_kernel(const float* __restrict__ Z, const int* __restrict__ ea,
                              const int* __restrict__ eb, float* __restrict__ out, int L) {
    int t = blockIdx.x * blockDim.x + threadIdx.x;
    int e = t >> 4;
    int c = (t & 15) << 2;
    if (e >= L) return;
    float4 za = *(const float4*)&Z[(size_t)ea[e] * 64 + c];
    float4 zb = *(const float4*)&Z[(size_t)eb[e] * 64 + c];
    float p = za.x * zb.x + za.y * zb.y + za.z * zb.z + za.w * zb.w;
    p += __shfl_xor(p, 1);
    p += __shfl_xor(p, 2);
    p += __shfl_xor(p, 4);
    p += __shfl_xor(p, 8);
    if ((t & 15) == 0) out[e] = p;
}

extern "C" void kernel_launch(void* const* d_in, const int* in_sizes, int n_in,
                              void* d_out, int out_size, void* d_ws, size_t ws_size,
                              hipStream_t stream) {
    const float* x   = (const float*)d_in[0];
    const int*   ei  = (const int*)d_in[1];   // [2,E] flat: src = ei, dst = ei+E
    const float* ew  = (const float*)d_in[2];
    const int*   eli = (const int*)d_in[3];   // [2,L] flat
    const float* W1  = (const float*)d_in[4];
    const float* b1  = (const float*)d_in[5];
    const float* W2  = (const float*)d_in[6];
    const float* b2  = (const float*)d_in[7];
    float* out = (float*)d_out;

    const int N = in_sizes[0] / 128;
    const int E = in_sizes[2];
    const int L = in_sizes[3] / 2;
    const int NP = ((N + 255) / 256) * 256;

    float* ws     = (float*)d_ws;
    float* dinv   = ws;                                  // NP
    int*   cnt    = (int*)(ws + NP);                     // NP (needs N+1)
    int*   rowptr = cnt + NP;                            // NP (needs N+1)
    int*   bsum   = rowptr + NP;                         // 1024
    int*   rank   = bsum + 1024;                         // E
    int2*  pairs  = (int2*)(rank + E);                   // E int2
    float* A      = (float*)(pairs + E);                 // NP*128
    float* B      = A + (size_t)NP * 128;                // NP*128

    const int n1 = N + 1;
    const int nb = (n1 + 1023) / 1024;

    hipMemsetAsync(cnt, 0, (size_t)n1 * 4, stream);
    hist_rank_kernel<<<(E + 255) / 256, 256, 0, stream>>>(ei + E, cnt, rank, E);
    scan_block<<<nb, 256, 0, stream>>>(cnt, rowptr, bsum, n1);
    scan_bsums<<<1, 256, 0, stream>>>(bsum, nb);
    scan_add<<<(n1 + 255) / 256, 256, 0, stream>>>(rowptr, bsum, n1);
    scatter_pairs<<<(E + 255) / 256, 256, 0, stream>>>(ei, ei + E, ew, rowptr, rank, pairs, E);
    deg_dinv_kernel<<<(N + 255) / 256, 256, 0, stream>>>(pairs, rowptr, dinv, N);
    norm_kernel<<<(E + 255) / 256, 256, 0, stream>>>(pairs, dinv, E);

    // layer 1: gemm then channel-split gather (2 serialized passes, half working set each)
    gemm_rt<128><<<(N + 63) / 64, 256, 0, stream>>>(x, W1, A, N);
    gather_reduce<128, 2, true><<<(N * 16 + 255) / 256, 256, 0, stream>>>(A, rowptr, pairs, dinv, b1, B, N, 0);
    gather_reduce<128, 2, true><<<(N * 16 + 255) / 256, 256, 0, stream>>>(A, rowptr, pairs, dinv, b1, B, N, 1);

    // layer 2
    gemm_rt<64><<<(N + 63) / 64, 256, 0, stream>>>(B, W2, A, N);
    gather_reduce<64, 1, false><<<(N * 16 + 255) / 256, 256, 0, stream>>>(A, rowptr, pairs, dinv, b2, B, N, 0);

    // decode
    decode_kernel<<<(L * 16 + 255) / 256, 256, 0, stream>>>(B, eli, eli + L, out, L);
}

// Round 8
// 532.131 us; speedup vs baseline: 1.0535x; 1.0020x over previous
//
#include <hip/hip_runtime.h>
#include <math.h>

// ---------------- PACKED: gemm128 (x@W1) + histogram/rank (independent work) ----------------
// blocks [0,Gg): register-tiled GEMM  Y[n,128] = X[n,128] @ W[128,128]  (M=64/block)
// blocks [Gg,..): grid-stride rank[e] = atomicAdd(&cnt[dst[e]],1)
// Rationale: GEMM is LDS/VALU-bound with idle memory pipes; hist is atomic-latency-bound
// with idle VALU/LDS. Packing hides one under the other (kernels serialize on the stream).
__global__ __launch_bounds__(256) void gemm128_hist_kernel(
        const float* __restrict__ X, const float* __restrict__ W, float* __restrict__ Y, int n,
        int Gg, const int* __restrict__ dst, int* __restrict__ cnt, int* __restrict__ rank, int E) {
    constexpr int CG  = 32;         // col-groups (4 cols each)
    constexpr int RG  = 8;          // row-groups
    constexpr int M   = 64;
    constexpr int RT  = 8;          // rows per thread
    constexpr int KC  = 32;
    constexpr int LDX = 132;
    __shared__ float  Xl[M * LDX];      // 33792 B
    __shared__ float4 Wl[KC * CG];      // 16384 B

    if (blockIdx.x >= Gg) {
        // ---- histogram + rank branch ----
        int stride = (gridDim.x - Gg) * 256;
        for (int e = (blockIdx.x - Gg) * 256 + threadIdx.x; e < E; e += stride)
            rank[e] = atomicAdd(&cnt[dst[e]], 1);
        return;
    }

    // ---- GEMM branch ----
    int t = threadIdx.x;
    int row0 = blockIdx.x * M;
    {
        const float4* Xg = (const float4*)X;
        for (int f = t; f < M * 32; f += 256) {
            int r = f >> 5, c4 = f & 31;
            int gr = row0 + r;
            float4 v = make_float4(0.f, 0.f, 0.f, 0.f);
            if (gr < n) v = Xg[(size_t)gr * 32 + c4];
            *(float4*)&Xl[r * LDX + c4 * 4] = v;
        }
    }

    int cg = t % CG;
    int r0 = (t / CG) * RT;

    float4 acc[RT];
#pragma unroll
    for (int r = 0; r < RT; r++) acc[r] = make_float4(0.f, 0.f, 0.f, 0.f);

    const float4* Wg = (const float4*)W;
    for (int kc = 0; kc < 128; kc += KC) {
        __syncthreads();
        for (int f = t; f < KC * CG; f += 256)
            Wl[f] = Wg[(size_t)kc * CG + f];
        __syncthreads();
#pragma unroll 4
        for (int k = 0; k < KC; k += 4) {
            float4 b0 = Wl[(k + 0) * CG + cg];
            float4 b1 = Wl[(k + 1) * CG + cg];
            float4 b2 = Wl[(k + 2) * CG + cg];
            float4 b3 = Wl[(k + 3) * CG + cg];
#pragma unroll
            for (int r = 0; r < RT; r++) {
                float4 a = *(float4*)&Xl[(r0 + r) * LDX + kc + k];
                acc[r].x += a.x * b0.x + a.y * b1.x + a.z * b2.x + a.w * b3.x;
                acc[r].y += a.x * b0.y + a.y * b1.y + a.z * b2.y + a.w * b3.y;
                acc[r].z += a.x * b0.z + a.y * b1.z + a.z * b2.z + a.w * b3.z;
                acc[r].w += a.x * b0.w + a.y * b1.w + a.z * b2.w + a.w * b3.w;
            }
        }
    }

#pragma unroll
    for (int r = 0; r < RT; r++) {
        int gr = row0 + r0 + r;
        if (gr < n) *(float4*)&Y[(size_t)gr * 128 + cg * 4] = acc[r];
    }
}

// exclusive scan, stage 1
__global__ __launch_bounds__(256) void scan_block(const int* __restrict__ in, int* __restrict__ out,
                                                  int* __restrict__ bsum, int n) {
    __shared__ int s[256];
    int tid = threadIdx.x;
    int base = blockIdx.x * 1024 + tid * 4;
    int a0 = (base + 0 < n) ? in[base + 0] : 0;
    int a1 = (base + 1 < n) ? in[base + 1] : 0;
    int a2 = (base + 2 < n) ? in[base + 2] : 0;
    int a3 = (base + 3 < n) ? in[base + 3] : 0;
    int tsum = a0 + a1 + a2 + a3;
    s[tid] = tsum;
    __syncthreads();
    for (int off = 1; off < 256; off <<= 1) {
        int v = (tid >= off) ? s[tid - off] : 0;
        __syncthreads();
        s[tid] += v;
        __syncthreads();
    }
    int texcl = s[tid] - tsum;
    if (base + 0 < n) out[base + 0] = texcl;
    if (base + 1 < n) out[base + 1] = texcl + a0;
    if (base + 2 < n) out[base + 2] = texcl + a0 + a1;
    if (base + 3 < n) out[base + 3] = texcl + a0 + a1 + a2;
    if (tid == 255) bsum[blockIdx.x] = s[255];
}

// stage 2: exclusive scan of block sums
__global__ __launch_bounds__(256) void scan_bsums(int* __restrict__ bsum, int nb) {
    __shared__ int s[256];
    __shared__ int carry_s;
    int tid = threadIdx.x;
    if (tid == 0) carry_s = 0;
    __syncthreads();
    for (int base = 0; base < nb; base += 256) {
        int v = (base + tid < nb) ? bsum[base + tid] : 0;
        int orig = v;
        s[tid] = v;
        __syncthreads();
        for (int off = 1; off < 256; off <<= 1) {
            int u = (tid >= off) ? s[tid - off] : 0;
            __syncthreads();
            s[tid] += u;
            __syncthreads();
        }
        int carry = carry_s;
        int excl = s[tid] - orig + carry;
        if (base + tid < nb) bsum[base + tid] = excl;
        int tot = s[255];
        __syncthreads();
        if (tid == 0) carry_s = carry + tot;
        __syncthreads();
    }
}

// stage 3: add block offsets
__global__ void scan_add(int* __restrict__ rowptr, const int* __restrict__ bscan, int n) {
    int t = blockIdx.x * blockDim.x + threadIdx.x;
    if (t < n) rowptr[t] += bscan[t >> 10];
}

// atomic-free CSR placement: pairs[rowptr[d] + rank[e]] = (src, ew)
__global__ void scatter_pairs(const int* __restrict__ src, const int* __restrict__ dst,
                              const float* __restrict__ ew, const int* __restrict__ rowptr,
                              const int* __restrict__ rank, int2* __restrict__ pairs, int E) {
    int e = blockIdx.x * blockDim.x + threadIdx.x;
    if (e >= E) return;
    int d = dst[e];
    int p = rowptr[d] + rank[e];
    pairs[p] = make_int2(src[e], __float_as_int(ew[e]));
}

// degree from sequential segment sum of sorted ew; dinv = 1/sqrt(deg+1)
__global__ void deg_dinv_kernel(const int2* __restrict__ pairs, const int* __restrict__ rowptr,
                                float* __restrict__ dinv, int n) {
    int i = blockIdx.x * blockDim.x + threadIdx.x;
    if (i >= n) return;
    int beg = rowptr[i], end = rowptr[i + 1];
    float s = 0.f;
    for (int j = beg; j < end; j++) s += __int_as_float(pairs[j].y);
    dinv[i] = 1.0f / sqrtf(s + 1.0f);   // self-loop weight folded in
}

// w' = dinv[src] * ew  (dinv[dst] factored out, applied in gather epilogue)
__global__ void norm_kernel(int2* __restrict__ pairs, const float* __restrict__ dinv, int E) {
    int j = blockIdx.x * blockDim.x + threadIdx.x;
    if (j >= E) return;
    int2 pr = pairs[j];
    pairs[j].y = __float_as_int(__int_as_float(pr.y) * dinv[pr.x]);
}

// ---------------- plain register-tiled GEMM (layer 2): Y[n,64] = X[n,128] @ W[128,64] ----------------
__global__ __launch_bounds__(256) void gemm_rt64(const float* __restrict__ X,
                                                 const float* __restrict__ W,
                                                 float* __restrict__ Y, int n) {
    constexpr int CG  = 16;
    constexpr int RG  = 16;
    constexpr int M   = 64;
    constexpr int RT  = 4;
    constexpr int KC  = 32;
    constexpr int LDX = 132;
    __shared__ float  Xl[M * LDX];
    __shared__ float4 Wl[KC * CG];

    int t = threadIdx.x;
    int row0 = blockIdx.x * M;
    {
        const float4* Xg = (const float4*)X;
        for (int f = t; f < M * 32; f += 256) {
            int r = f >> 5, c4 = f & 31;
            int gr = row0 + r;
            float4 v = make_float4(0.f, 0.f, 0.f, 0.f);
            if (gr < n) v = Xg[(size_t)gr * 32 + c4];
            *(float4*)&Xl[r * LDX + c4 * 4] = v;
        }
    }

    int cg = t % CG;
    int r0 = (t / CG) * RT;

    float4 acc[RT];
#pragma unroll
    for (int r = 0; r < RT; r++) acc[r] = make_float4(0.f, 0.f, 0.f, 0.f);

    const float4* Wg = (const float4*)W;
    for (int kc = 0; kc < 128; kc += KC) {
        __syncthreads();
        for (int f = t; f < KC * CG; f += 256)
            Wl[f] = Wg[(size_t)kc * CG + f];
        __syncthreads();
#pragma unroll 4
        for (int k = 0; k < KC; k += 4) {
            float4 b0 = Wl[(k + 0) * CG + cg];
            float4 b1 = Wl[(k + 1) * CG + cg];
            float4 b2 = Wl[(k + 2) * CG + cg];
            float4 b3 = Wl[(k + 3) * CG + cg];
#pragma unroll
            for (int r = 0; r < RT; r++) {
                float4 a = *(float4*)&Xl[(r0 + r) * LDX + kc + k];
                acc[r].x += a.x * b0.x + a.y * b1.x + a.z * b2.x + a.w * b3.x;
                acc[r].y += a.x * b0.y + a.y * b1.y + a.z * b2.y + a.w * b3.y;
                acc[r].z += a.x * b0.z + a.y * b1.z + a.z * b2.z + a.w * b3.z;
                acc[r].w += a.x * b0.w + a.y * b1.w + a.z * b2.w + a.w * b3.w;
            }
        }
    }

#pragma unroll
    for (int r = 0; r < RT; r++) {
        int gr = row0 + r0 + r;
        if (gr < n) *(float4*)&Y[(size_t)gr * 64 + cg * 4] = acc[r];
    }
}

// ---------------- CSR segmented gather-reduce, 8-deep explicit MLP ----------------
// out = di*(sum_j w'_j H[s_j] + di*H[node]) + bias,  w' = dinv[src]*ew
template<int C, bool RELU>
__global__ __launch_bounds__(256) void gather_reduce(const float* __restrict__ H,
                                                     const int* __restrict__ rowptr,
                                                     const int2* __restrict__ pairs,
                                                     const float* __restrict__ dinv,
                                                     const float* __restrict__ bias,
                                                     float* __restrict__ out, int n) {
    constexpr int TPN = C / 4;
    int t = blockIdx.x * blockDim.x + threadIdx.x;
    int node = t / TPN;
    int c4 = t % TPN;
    if (node >= n) return;
    const float4* H4 = (const float4*)H;
    int beg = rowptr[node], end = rowptr[node + 1];
    float di = dinv[node];
    float4 hv = H4[(size_t)node * TPN + c4];
    float4 bb = ((const float4*)bias)[c4];
    float4 a0, a1, a2, a3;
    a0.x = hv.x * di; a0.y = hv.y * di; a0.z = hv.z * di; a0.w = hv.w * di;
    a1 = make_float4(0.f, 0.f, 0.f, 0.f);
    a2 = make_float4(0.f, 0.f, 0.f, 0.f);
    a3 = make_float4(0.f, 0.f, 0.f, 0.f);
    int j = beg;
    for (; j + 8 <= end; j += 8) {
        int2 p0 = pairs[j + 0], p1 = pairs[j + 1], p2 = pairs[j + 2], p3 = pairs[j + 3];
        int2 p4 = pairs[j + 4], p5 = pairs[j + 5], p6 = pairs[j + 6], p7 = pairs[j + 7];
        float4 v0 = H4[(size_t)p0.x * TPN + c4];
        float4 v1 = H4[(size_t)p1.x * TPN + c4];
        float4 v2 = H4[(size_t)p2.x * TPN + c4];
        float4 v3 = H4[(size_t)p3.x * TPN + c4];
        float4 v4 = H4[(size_t)p4.x * TPN + c4];
        float4 v5 = H4[(size_t)p5.x * TPN + c4];
        float4 v6 = H4[(size_t)p6.x * TPN + c4];
        float4 v7 = H4[(size_t)p7.x * TPN + c4];
        float w0 = __int_as_float(p0.y), w1 = __int_as_float(p1.y);
        float w2 = __int_as_float(p2.y), w3 = __int_as_float(p3.y);
        float w4 = __int_as_float(p4.y), w5 = __int_as_float(p5.y);
        float w6 = __int_as_float(p6.y), w7 = __int_as_float(p7.y);
        a0.x += v0.x * w0; a0.y += v0.y * w0; a0.z += v0.z * w0; a0.w += v0.w * w0;
        a1.x += v1.x * w1; a1.y += v1.y * w1; a1.z += v1.z * w1; a1.w += v1.w * w1;
        a2.x += v2.x * w2; a2.y += v2.y * w2; a2.z += v2.z * w2; a2.w += v2.w * w2;
        a3.x += v3.x * w3; a3.y += v3.y * w3; a3.z += v3.z * w3; a3.w += v3.w * w3;
        a0.x += v4.x * w4; a0.y += v4.y * w4; a0.z += v4.z * w4; a0.w += v4.w * w4;
        a1.x += v5.x * w5; a1.y += v5.y * w5; a1.z += v5.z * w5; a1.w += v5.w * w5;
        a2.x += v6.x * w6; a2.y += v6.y * w6; a2.z += v6.z * w6; a2.w += v6.w * w6;
        a3.x += v7.x * w7; a3.y += v7.y * w7; a3.z += v7.z * w7; a3.w += v7.w * w7;
    }
    if (j + 4 <= end) {
        int2 p0 = pairs[j + 0], p1 = pairs[j + 1], p2 = pairs[j + 2], p3 = pairs[j + 3];
        float4 v0 = H4[(size_t)p0.x * TPN + c4];
        float4 v1 = H4[(size_t)p1.x * TPN + c4];
        float4 v2 = H4[(size_t)p2.x * TPN + c4];
        float4 v3 = H4[(size_t)p3.x * TPN + c4];
        float w0 = __int_as_float(p0.y), w1 = __int_as_float(p1.y);
        float w2 = __int_as_float(p2.y), w3 = __int_as_float(p3.y);
        a0.x += v0.x * w0; a0.y += v0.y * w0; a0.z += v0.z * w0; a0.w += v0.w * w0;
        a1.x += v1.x * w1; a1.y += v1.y * w1; a1.z += v1.z * w1; a1.w += v1.w * w1;
        a2.x += v2.x * w2; a2.y += v2.y * w2; a2.z += v2.z * w2; a2.w += v2.w * w2;
        a3.x += v3.x * w3; a3.y += v3.y * w3; a3.z += v3.z * w3; a3.w += v3.w * w3;
        j += 4;
    }
    for (; j < end; j++) {
        int2 pr = pairs[j];
        float w = __int_as_float(pr.y);
        float4 v = H4[(size_t)pr.x * TPN + c4];
        a0.x += v.x * w; a0.y += v.y * w; a0.z += v.z * w; a0.w += v.w * w;
    }
    float4 acc;
    acc.x = ((a0.x + a1.x) + (a2.x + a3.x)) * di + bb.x;
    acc.y = ((a0.y + a1.y) + (a2.y + a3.y)) * di + bb.y;
    acc.z = ((a0.z + a1.z) + (a2.z + a3.z)) * di + bb.z;
    acc.w = ((a0.w + a1.w) + (a2.w + a3.w)) * di + bb.w;
    if (RELU) {
        acc.x = fmaxf(acc.x, 0.f);
        acc.y = fmaxf(acc.y, 0.f);
        acc.z = fmaxf(acc.z, 0.f);
        acc.w = fmaxf(acc.w, 0.f);
    }
    *(float4*)&out[(size_t)node * C + c4 * 4] = acc;
}

// ---------------- decode ----------------
__global__ void decode_kernel(const float* __restrict__ Z, const int* __restrict__ ea,
                              const int* __restrict__ eb, float* __restrict__ out, int L) {
    int t = blockIdx.x * blockDim.x + threadIdx.x;
    int e = t >> 4;
    int c = (t & 15) << 2;
    if (e >= L) return;
    float4 za = *(const float4*)&Z[(size_t)ea[e] * 64 + c];
    float4 zb = *(const float4*)&Z[(size_t)eb[e] * 64 + c];
    float p = za.x * zb.x + za.y * zb.y + za.z * zb.z + za.w * zb.w;
    p += __shfl_xor(p, 1);
    p += __shfl_xor(p, 2);
    p += __shfl_xor(p, 4);
    p += __shfl_xor(p, 8);
    if ((t & 15) == 0) out[e] = p;
}

extern "C" void kernel_launch(void* const* d_in, const int* in_sizes, int n_in,
                              void* d_out, int out_size, void* d_ws, size_t ws_size,
                              hipStream_t stream) {
    const float* x   = (const float*)d_in[0];
    const int*   ei  = (const int*)d_in[1];   // [2,E] flat: src = ei, dst = ei+E
    const float* ew  = (const float*)d_in[2];
    const int*   eli = (const int*)d_in[3];   // [2,L] flat
    const float* W1  = (const float*)d_in[4];
    const float* b1  = (const float*)d_in[5];
    const float* W2  = (const float*)d_in[6];
    const float* b2  = (const float*)d_in[7];
    float* out = (float*)d_out;

    const int N = in_sizes[0] / 128;
    const int E = in_sizes[2];
    const int L = in_sizes[3] / 2;
    const int NP = ((N + 255) / 256) * 256;

    float* ws     = (float*)d_ws;
    float* dinv   = ws;                                  // NP
    int*   cnt    = (int*)(ws + NP);                     // NP (needs N+1)
    int*   rowptr = cnt + NP;                            // NP (needs N+1)
    int*   bsum   = rowptr + NP;                         // 1024
    int*   rank   = bsum + 1024;                         // E
    int2*  pairs  = (int2*)(rank + E);                   // E int2
    float* A      = (float*)(pairs + E);                 // NP*128
    float* B      = A + (size_t)NP * 128;                // NP*128

    const int n1 = N + 1;
    const int nb = (n1 + 1023) / 1024;

    hipMemsetAsync(cnt, 0, (size_t)n1 * 4, stream);

    // packed: layer-1 GEMM + histogram/rank (independent, hide atomic latency under VALU work)
    const int Gg = (N + 63) / 64;
    const int Gh = 2048;
    gemm128_hist_kernel<<<Gg + Gh, 256, 0, stream>>>(x, W1, A, N, Gg, ei + E, cnt, rank, E);

    // CSR finish
    scan_block<<<nb, 256, 0, stream>>>(cnt, rowptr, bsum, n1);
    scan_bsums<<<1, 256, 0, stream>>>(bsum, nb);
    scan_add<<<(n1 + 255) / 256, 256, 0, stream>>>(rowptr, bsum, n1);
    scatter_pairs<<<(E + 255) / 256, 256, 0, stream>>>(ei, ei + E, ew, rowptr, rank, pairs, E);
    deg_dinv_kernel<<<(N + 255) / 256, 256, 0, stream>>>(pairs, rowptr, dinv, N);
    norm_kernel<<<(E + 255) / 256, 256, 0, stream>>>(pairs, dinv, E);

    // layer 1 aggregate (unsplit — channel-split regressed)
    gather_reduce<128, true><<<(N * 32 + 255) / 256, 256, 0, stream>>>(A, rowptr, pairs, dinv, b1, B, N);

    // layer 2
    gemm_rt64<<<(N + 63) / 64, 256, 0, stream>>>(B, W2, A, N);
    gather_reduce<64, false><<<(N * 16 + 255) / 256, 256, 0, stream>>>(A, rowptr, pairs, dinv, b2, B, N);

    // decode
    decode_kernel<<<(L * 16 + 255) / 256, 256, 0, stream>>>(B, eli, eli + L, out, L);
}

// Round 9
// 523.746 us; speedup vs baseline: 1.0704x; 1.0160x over previous
//
#include <hip/hip_runtime.h>
#include <math.h>

// ---------------- STAGGER-FUSED: every block does ONE GEMM tile AND one hist slice ----------------
// Order alternates by blockIdx parity so ~half the resident blocks issue atomics while the
// other half issue VALU/LDS work -> fabric-atomic latency hides under GEMM compute.
__global__ __launch_bounds__(256) void gemm128_hist_kernel(
        const float* __restrict__ X, const float* __restrict__ W, float* __restrict__ Y, int n,
        const int* __restrict__ dst, int* __restrict__ cnt, int* __restrict__ rank, int E) {
    constexpr int CG  = 32;
    constexpr int RG  = 8;
    constexpr int M   = 64;
    constexpr int RT  = 8;
    constexpr int KC  = 32;
    constexpr int LDX = 132;
    __shared__ float  Xl[M * LDX];      // 33792 B
    __shared__ float4 Wl[KC * CG];      // 16384 B

    const int bid = blockIdx.x;
    const int t = threadIdx.x;
    const int EPB = (E + (int)gridDim.x - 1) / (int)gridDim.x;
    const int eBeg = bid * EPB;
    const int eEnd = min(eBeg + EPB, E);

    // ---- hist slice (first for even blocks) ----
    if ((bid & 1) == 0) {
        for (int e = eBeg + t; e < eEnd; e += 256)
            rank[e] = atomicAdd(&cnt[dst[e]], 1);
    }

    // ---- GEMM tile ----
    int row0 = bid * M;
    {
        const float4* Xg = (const float4*)X;
        for (int f = t; f < M * 32; f += 256) {
            int r = f >> 5, c4 = f & 31;
            int gr = row0 + r;
            float4 v = make_float4(0.f, 0.f, 0.f, 0.f);
            if (gr < n) v = Xg[(size_t)gr * 32 + c4];
            *(float4*)&Xl[r * LDX + c4 * 4] = v;
        }
    }

    int cg = t % CG;
    int r0 = (t / CG) * RT;

    float4 acc[RT];
#pragma unroll
    for (int r = 0; r < RT; r++) acc[r] = make_float4(0.f, 0.f, 0.f, 0.f);

    const float4* Wg = (const float4*)W;
    for (int kc = 0; kc < 128; kc += KC) {
        __syncthreads();
        for (int f = t; f < KC * CG; f += 256)
            Wl[f] = Wg[(size_t)kc * CG + f];
        __syncthreads();
#pragma unroll 4
        for (int k = 0; k < KC; k += 4) {
            float4 b0 = Wl[(k + 0) * CG + cg];
            float4 b1 = Wl[(k + 1) * CG + cg];
            float4 b2 = Wl[(k + 2) * CG + cg];
            float4 b3 = Wl[(k + 3) * CG + cg];
#pragma unroll
            for (int r = 0; r < RT; r++) {
                float4 a = *(float4*)&Xl[(r0 + r) * LDX + kc + k];
                acc[r].x += a.x * b0.x + a.y * b1.x + a.z * b2.x + a.w * b3.x;
                acc[r].y += a.x * b0.y + a.y * b1.y + a.z * b2.y + a.w * b3.y;
                acc[r].z += a.x * b0.z + a.y * b1.z + a.z * b2.z + a.w * b3.z;
                acc[r].w += a.x * b0.w + a.y * b1.w + a.z * b2.w + a.w * b3.w;
            }
        }
    }

#pragma unroll
    for (int r = 0; r < RT; r++) {
        int gr = row0 + r0 + r;
        if (gr < n) *(float4*)&Y[(size_t)gr * 128 + cg * 4] = acc[r];
    }

    // ---- hist slice (after GEMM for odd blocks) ----
    if (bid & 1) {
        for (int e = eBeg + t; e < eEnd; e += 256)
            rank[e] = atomicAdd(&cnt[dst[e]], 1);
    }
}

// exclusive scan, stage 1
__global__ __launch_bounds__(256) void scan_block(const int* __restrict__ in, int* __restrict__ out,
                                                  int* __restrict__ bsum, int n) {
    __shared__ int s[256];
    int tid = threadIdx.x;
    int base = blockIdx.x * 1024 + tid * 4;
    int a0 = (base + 0 < n) ? in[base + 0] : 0;
    int a1 = (base + 1 < n) ? in[base + 1] : 0;
    int a2 = (base + 2 < n) ? in[base + 2] : 0;
    int a3 = (base + 3 < n) ? in[base + 3] : 0;
    int tsum = a0 + a1 + a2 + a3;
    s[tid] = tsum;
    __syncthreads();
    for (int off = 1; off < 256; off <<= 1) {
        int v = (tid >= off) ? s[tid - off] : 0;
        __syncthreads();
        s[tid] += v;
        __syncthreads();
    }
    int texcl = s[tid] - tsum;
    if (base + 0 < n) out[base + 0] = texcl;
    if (base + 1 < n) out[base + 1] = texcl + a0;
    if (base + 2 < n) out[base + 2] = texcl + a0 + a1;
    if (base + 3 < n) out[base + 3] = texcl + a0 + a1 + a2;
    if (tid == 255) bsum[blockIdx.x] = s[255];
}

// stage 2: exclusive scan of block sums
__global__ __launch_bounds__(256) void scan_bsums(int* __restrict__ bsum, int nb) {
    __shared__ int s[256];
    __shared__ int carry_s;
    int tid = threadIdx.x;
    if (tid == 0) carry_s = 0;
    __syncthreads();
    for (int base = 0; base < nb; base += 256) {
        int v = (base + tid < nb) ? bsum[base + tid] : 0;
        int orig = v;
        s[tid] = v;
        __syncthreads();
        for (int off = 1; off < 256; off <<= 1) {
            int u = (tid >= off) ? s[tid - off] : 0;
            __syncthreads();
            s[tid] += u;
            __syncthreads();
        }
        int carry = carry_s;
        int excl = s[tid] - orig + carry;
        if (base + tid < nb) bsum[base + tid] = excl;
        int tot = s[255];
        __syncthreads();
        if (tid == 0) carry_s = carry + tot;
        __syncthreads();
    }
}

// stage 3: add block offsets
__global__ void scan_add(int* __restrict__ rowptr, const int* __restrict__ bscan, int n) {
    int t = blockIdx.x * blockDim.x + threadIdx.x;
    if (t < n) rowptr[t] += bscan[t >> 10];
}

// atomic-free CSR placement: pairs[rowptr[d] + rank[e]] = (src, ew)
__global__ void scatter_pairs(const int* __restrict__ src, const int* __restrict__ dst,
                              const float* __restrict__ ew, const int* __restrict__ rowptr,
                              const int* __restrict__ rank, int2* __restrict__ pairs, int E) {
    int e = blockIdx.x * blockDim.x + threadIdx.x;
    if (e >= E) return;
    int d = dst[e];
    int p = rowptr[d] + rank[e];
    pairs[p] = make_int2(src[e], __float_as_int(ew[e]));
}

// degree from sequential segment sum of sorted ew; dinv = 1/sqrt(deg+1)
__global__ void deg_dinv_kernel(const int2* __restrict__ pairs, const int* __restrict__ rowptr,
                                float* __restrict__ dinv, int n) {
    int i = blockIdx.x * blockDim.x + threadIdx.x;
    if (i >= n) return;
    int beg = rowptr[i], end = rowptr[i + 1];
    float s = 0.f;
    for (int j = beg; j < end; j++) s += __int_as_float(pairs[j].y);
    dinv[i] = 1.0f / sqrtf(s + 1.0f);   // self-loop weight folded in
}

// w' = dinv[src] * ew  (dinv[dst] factored out, applied in gather epilogue)
__global__ void norm_kernel(int2* __restrict__ pairs, const float* __restrict__ dinv, int E) {
    int j = blockIdx.x * blockDim.x + threadIdx.x;
    if (j >= E) return;
    int2 pr = pairs[j];
    pairs[j].y = __float_as_int(__int_as_float(pr.y) * dinv[pr.x]);
}

// ---------------- plain register-tiled GEMM (layer 2): Y[n,64] = X[n,128] @ W[128,64] ----------------
__global__ __launch_bounds__(256) void gemm_rt64(const float* __restrict__ X,
                                                 const float* __restrict__ W,
                                                 float* __restrict__ Y, int n) {
    constexpr int CG  = 16;
    constexpr int RG  = 16;
    constexpr int M   = 64;
    constexpr int RT  = 4;
    constexpr int KC  = 32;
    constexpr int LDX = 132;
    __shared__ float  Xl[M * LDX];
    __shared__ float4 Wl[KC * CG];

    int t = threadIdx.x;
    int row0 = blockIdx.x * M;
    {
        const float4* Xg = (const float4*)X;
        for (int f = t; f < M * 32; f += 256) {
            int r = f >> 5, c4 = f & 31;
            int gr = row0 + r;
            float4 v = make_float4(0.f, 0.f, 0.f, 0.f);
            if (gr < n) v = Xg[(size_t)gr * 32 + c4];
            *(float4*)&Xl[r * LDX + c4 * 4] = v;
        }
    }

    int cg = t % CG;
    int r0 = (t / CG) * RT;

    float4 acc[RT];
#pragma unroll
    for (int r = 0; r < RT; r++) acc[r] = make_float4(0.f, 0.f, 0.f, 0.f);

    const float4* Wg = (const float4*)W;
    for (int kc = 0; kc < 128; kc += KC) {
        __syncthreads();
        for (int f = t; f < KC * CG; f += 256)
            Wl[f] = Wg[(size_t)kc * CG + f];
        __syncthreads();
#pragma unroll 4
        for (int k = 0; k < KC; k += 4) {
            float4 b0 = Wl[(k + 0) * CG + cg];
            float4 b1 = Wl[(k + 1) * CG + cg];
            float4 b2 = Wl[(k + 2) * CG + cg];
            float4 b3 = Wl[(k + 3) * CG + cg];
#pragma unroll
            for (int r = 0; r < RT; r++) {
                float4 a = *(float4*)&Xl[(r0 + r) * LDX + kc + k];
                acc[r].x += a.x * b0.x + a.y * b1.x + a.z * b2.x + a.w * b3.x;
                acc[r].y += a.x * b0.y + a.y * b1.y + a.z * b2.y + a.w * b3.y;
                acc[r].z += a.x * b0.z + a.y * b1.z + a.z * b2.z + a.w * b3.z;
                acc[r].w += a.x * b0.w + a.y * b1.w + a.z * b2.w + a.w * b3.w;
            }
        }
    }

#pragma unroll
    for (int r = 0; r < RT; r++) {
        int gr = row0 + r0 + r;
        if (gr < n) *(float4*)&Y[(size_t)gr * 64 + cg * 4] = acc[r];
    }
}

// ---------------- CSR segmented gather-reduce, 8-deep explicit MLP ----------------
// out = di*(sum_j w'_j H[s_j] + di*H[node]) + bias,  w' = dinv[src]*ew
template<int C, bool RELU>
__global__ __launch_bounds__(256) void gather_reduce(const float* __restrict__ H,
                                                     const int* __restrict__ rowptr,
                                                     const int2* __restrict__ pairs,
                                                     const float* __restrict__ dinv,
                                                     const float* __restrict__ bias,
                                                     float* __restrict__ out, int n) {
    constexpr int TPN = C / 4;
    int t = blockIdx.x * blockDim.x + threadIdx.x;
    int node = t / TPN;
    int c4 = t % TPN;
    if (node >= n) return;
    const float4* H4 = (const float4*)H;
    int beg = rowptr[node], end = rowptr[node + 1];
    float di = dinv[node];
    float4 hv = H4[(size_t)node * TPN + c4];
    float4 bb = ((const float4*)bias)[c4];
    float4 a0, a1, a2, a3;
    a0.x = hv.x * di; a0.y = hv.y * di; a0.z = hv.z * di; a0.w = hv.w * di;
    a1 = make_float4(0.f, 0.f, 0.f, 0.f);
    a2 = make_float4(0.f, 0.f, 0.f, 0.f);
    a3 = make_float4(0.f, 0.f, 0.f, 0.f);
    int j = beg;
    for (; j + 8 <= end; j += 8) {
        int2 p0 = pairs[j + 0], p1 = pairs[j + 1], p2 = pairs[j + 2], p3 = pairs[j + 3];
        int2 p4 = pairs[j + 4], p5 = pairs[j + 5], p6 = pairs[j + 6], p7 = pairs[j + 7];
        float4 v0 = H4[(size_t)p0.x * TPN + c4];
        float4 v1 = H4[(size_t)p1.x * TPN + c4];
        float4 v2 = H4[(size_t)p2.x * TPN + c4];
        float4 v3 = H4[(size_t)p3.x * TPN + c4];
        float4 v4 = H4[(size_t)p4.x * TPN + c4];
        float4 v5 = H4[(size_t)p5.x * TPN + c4];
        float4 v6 = H4[(size_t)p6.x * TPN + c4];
        float4 v7 = H4[(size_t)p7.x * TPN + c4];
        float w0 = __int_as_float(p0.y), w1 = __int_as_float(p1.y);
        float w2 = __int_as_float(p2.y), w3 = __int_as_float(p3.y);
        float w4 = __int_as_float(p4.y), w5 = __int_as_float(p5.y);
        float w6 = __int_as_float(p6.y), w7 = __int_as_float(p7.y);
        a0.x += v0.x * w0; a0.y += v0.y * w0; a0.z += v0.z * w0; a0.w += v0.w * w0;
        a1.x += v1.x * w1; a1.y += v1.y * w1; a1.z += v1.z * w1; a1.w += v1.w * w1;
        a2.x += v2.x * w2; a2.y += v2.y * w2; a2.z += v2.z * w2; a2.w += v2.w * w2;
        a3.x += v3.x * w3; a3.y += v3.y * w3; a3.z += v3.z * w3; a3.w += v3.w * w3;
        a0.x += v4.x * w4; a0.y += v4.y * w4; a0.z += v4.z * w4; a0.w += v4.w * w4;
        a1.x += v5.x * w5; a1.y += v5.y * w5; a1.z += v5.z * w5; a1.w += v5.w * w5;
        a2.x += v6.x * w6; a2.y += v6.y * w6; a2.z += v6.z * w6; a2.w += v6.w * w6;
        a3.x += v7.x * w7; a3.y += v7.y * w7; a3.z += v7.z * w7; a3.w += v7.w * w7;
    }
    if (j + 4 <= end) {
        int2 p0 = pairs[j + 0], p1 = pairs[j + 1], p2 = pairs[j + 2], p3 = pairs[j + 3];
        float4 v0 = H4[(size_t)p0.x * TPN + c4];
        float4 v1 = H4[(size_t)p1.x * TPN + c4];
        float4 v2 = H4[(size_t)p2.x * TPN + c4];
        float4 v3 = H4[(size_t)p3.x * TPN + c4];
        float w0 = __int_as_float(p0.y), w1 = __int_as_float(p1.y);
        float w2 = __int_as_float(p2.y), w3 = __int_as_float(p3.y);
        a0.x += v0.x * w0; a0.y += v0.y * w0; a0.z += v0.z * w0; a0.w += v0.w * w0;
        a1.x += v1.x * w1; a1.y += v1.y * w1; a1.z += v1.z * w1; a1.w += v1.w * w1;
        a2.x += v2.x * w2; a2.y += v2.y * w2; a2.z += v2.z * w2; a2.w += v2.w * w2;
        a3.x += v3.x * w3; a3.y += v3.y * w3; a3.z += v3.z * w3; a3.w += v3.w * w3;
        j += 4;
    }
    for (; j < end; j++) {
        int2 pr = pairs[j];
        float w = __int_as_float(pr.y);
        float4 v = H4[(size_t)pr.x * TPN + c4];
        a0.x += v.x * w; a0.y += v.y * w; a0.z += v.z * w; a0.w += v.w * w;
    }
    float4 acc;
    acc.x = ((a0.x + a1.x) + (a2.x + a3.x)) * di + bb.x;
    acc.y = ((a0.y + a1.y) + (a2.y + a3.y)) * di + bb.y;
    acc.z = ((a0.z + a1.z) + (a2.z + a3.z)) * di + bb.z;
    acc.w = ((a0.w + a1.w) + (a2.w + a3.w)) * di + bb.w;
    if (RELU) {
        acc.x = fmaxf(acc.x, 0.f);
        acc.y = fmaxf(acc.y, 0.f);
        acc.z = fmaxf(acc.z, 0.f);
        acc.w = fmaxf(acc.w, 0.f);
    }
    *(float4*)&out[(size_t)node * C + c4 * 4] = acc;
}

// ---------------- decode ----------------
__global__ void decode_kernel(const float* __restrict__ Z, const int* __restrict__ ea,
                              const int* __restrict__ eb, float* __restrict__ out, int L) {
    int t = blockIdx.x * blockDim.x + threadIdx.x;
    int e = t >> 4;
    int c = (t & 15) << 2;
    if (e >= L) return;
    float4 za = *(const float4*)&Z[(size_t)ea[e] * 64 + c];
    float4 zb = *(const float4*)&Z[(size_t)eb[e] * 64 + c];
    float p = za.x * zb.x + za.y * zb.y + za.z * zb.z + za.w * zb.w;
    p += __shfl_xor(p, 1);
    p += __shfl_xor(p, 2);
    p += __shfl_xor(p, 4);
    p += __shfl_xor(p, 8);
    if ((t & 15) == 0) out[e] = p;
}

extern "C" void kernel_launch(void* const* d_in, const int* in_sizes, int n_in,
                              void* d_out, int out_size, void* d_ws, size_t ws_size,
                              hipStream_t stream) {
    const float* x   = (const float*)d_in[0];
    const int*   ei  = (const int*)d_in[1];   // [2,E] flat: src = ei, dst = ei+E
    const float* ew  = (const float*)d_in[2];
    const int*   eli = (const int*)d_in[3];   // [2,L] flat
    const float* W1  = (const float*)d_in[4];
    const float* b1  = (const float*)d_in[5];
    const float* W2  = (const float*)d_in[6];
    const float* b2  = (const float*)d_in[7];
    float* out = (float*)d_out;

    const int N = in_sizes[0] / 128;
    const int E = in_sizes[2];
    const int L = in_sizes[3] / 2;
    const int NP = ((N + 255) / 256) * 256;

    float* ws     = (float*)d_ws;
    float* dinv   = ws;                                  // NP
    int*   cnt    = (int*)(ws + NP);                     // NP (needs N+1)
    int*   rowptr = cnt + NP;                            // NP (needs N+1)
    int*   bsum   = rowptr + NP;                         // 1024
    int*   rank   = bsum + 1024;                         // E
    int2*  pairs  = (int2*)(rank + E);                   // E int2
    float* A      = (float*)(pairs + E);                 // NP*128
    float* B      = A + (size_t)NP * 128;                // NP*128

    const int n1 = N + 1;
    const int nb = (n1 + 1023) / 1024;

    hipMemsetAsync(cnt, 0, (size_t)n1 * 4, stream);

    // stagger-fused: layer-1 GEMM tiles + histogram/rank slices in the same blocks
    const int Gg = (N + 63) / 64;
    gemm128_hist_kernel<<<Gg, 256, 0, stream>>>(x, W1, A, N, ei + E, cnt, rank, E);

    // CSR finish
    scan_block<<<nb, 256, 0, stream>>>(cnt, rowptr, bsum, n1);
    scan_bsums<<<1, 256, 0, stream>>>(bsum, nb);
    scan_add<<<(n1 + 255) / 256, 256, 0, stream>>>(rowptr, bsum, n1);
    scatter_pairs<<<(E + 255) / 256, 256, 0, stream>>>(ei, ei + E, ew, rowptr, rank, pairs, E);
    deg_dinv_kernel<<<(N + 255) / 256, 256, 0, stream>>>(pairs, rowptr, dinv, N);
    norm_kernel<<<(E + 255) / 256, 256, 0, stream>>>(pairs, dinv, E);

    // layer 1 aggregate
    gather_reduce<128, true><<<(N * 32 + 255) / 256, 256, 0, stream>>>(A, rowptr, pairs, dinv, b1, B, N);

    // layer 2
    gemm_rt64<<<(N + 63) / 64, 256, 0, stream>>>(B, W2, A, N);
    gather_reduce<64, false><<<(N * 16 + 255) / 256, 256, 0, stream>>>(A, rowptr, pairs, dinv, b2, B, N);

    // decode
    decode_kernel<<<(L * 16 + 255) / 256, 256, 0, stream>>>(B, eli, eli + L, out, L);
}

// Round 10
// 491.929 us; speedup vs baseline: 1.1396x; 1.0647x over previous
//
#include <hip/hip_runtime.h>
#include <math.h>

// ---------------- STAGGER-FUSED: every block does ONE GEMM tile AND one hist slice ----------------
__global__ __launch_bounds__(256) void gemm128_hist_kernel(
        const float* __restrict__ X, const float* __restrict__ W, float* __restrict__ Y, int n,
        const int* __restrict__ dst, int* __restrict__ cnt, int* __restrict__ rank, int E) {
    constexpr int CG  = 32;
    constexpr int RG  = 8;
    constexpr int M   = 64;
    constexpr int RT  = 8;
    constexpr int KC  = 32;
    constexpr int LDX = 132;
    __shared__ float  Xl[M * LDX];      // 33792 B
    __shared__ float4 Wl[KC * CG];      // 16384 B

    const int bid = blockIdx.x;
    const int t = threadIdx.x;
    const int EPB = (E + (int)gridDim.x - 1) / (int)gridDim.x;
    const int eBeg = bid * EPB;
    const int eEnd = min(eBeg + EPB, E);

    if ((bid & 1) == 0) {
        for (int e = eBeg + t; e < eEnd; e += 256)
            rank[e] = atomicAdd(&cnt[dst[e]], 1);
    }

    int row0 = bid * M;
    {
        const float4* Xg = (const float4*)X;
        for (int f = t; f < M * 32; f += 256) {
            int r = f >> 5, c4 = f & 31;
            int gr = row0 + r;
            float4 v = make_float4(0.f, 0.f, 0.f, 0.f);
            if (gr < n) v = Xg[(size_t)gr * 32 + c4];
            *(float4*)&Xl[r * LDX + c4 * 4] = v;
        }
    }

    int cg = t % CG;
    int r0 = (t / CG) * RT;

    float4 acc[RT];
#pragma unroll
    for (int r = 0; r < RT; r++) acc[r] = make_float4(0.f, 0.f, 0.f, 0.f);

    const float4* Wg = (const float4*)W;
    for (int kc = 0; kc < 128; kc += KC) {
        __syncthreads();
        for (int f = t; f < KC * CG; f += 256)
            Wl[f] = Wg[(size_t)kc * CG + f];
        __syncthreads();
#pragma unroll 4
        for (int k = 0; k < KC; k += 4) {
            float4 b0 = Wl[(k + 0) * CG + cg];
            float4 b1 = Wl[(k + 1) * CG + cg];
            float4 b2 = Wl[(k + 2) * CG + cg];
            float4 b3 = Wl[(k + 3) * CG + cg];
#pragma unroll
            for (int r = 0; r < RT; r++) {
                float4 a = *(float4*)&Xl[(r0 + r) * LDX + kc + k];
                acc[r].x += a.x * b0.x + a.y * b1.x + a.z * b2.x + a.w * b3.x;
                acc[r].y += a.x * b0.y + a.y * b1.y + a.z * b2.y + a.w * b3.y;
                acc[r].z += a.x * b0.z + a.y * b1.z + a.z * b2.z + a.w * b3.z;
                acc[r].w += a.x * b0.w + a.y * b1.w + a.z * b2.w + a.w * b3.w;
            }
        }
    }

#pragma unroll
    for (int r = 0; r < RT; r++) {
        int gr = row0 + r0 + r;
        if (gr < n) *(float4*)&Y[(size_t)gr * 128 + cg * 4] = acc[r];
    }

    if (bid & 1) {
        for (int e = eBeg + t; e < eEnd; e += 256)
            rank[e] = atomicAdd(&cnt[dst[e]], 1);
    }
}

// exclusive scan, stage 1
__global__ __launch_bounds__(256) void scan_block(const int* __restrict__ in, int* __restrict__ out,
                                                  int* __restrict__ bsum, int n) {
    __shared__ int s[256];
    int tid = threadIdx.x;
    int base = blockIdx.x * 1024 + tid * 4;
    int a0 = (base + 0 < n) ? in[base + 0] : 0;
    int a1 = (base + 1 < n) ? in[base + 1] : 0;
    int a2 = (base + 2 < n) ? in[base + 2] : 0;
    int a3 = (base + 3 < n) ? in[base + 3] : 0;
    int tsum = a0 + a1 + a2 + a3;
    s[tid] = tsum;
    __syncthreads();
    for (int off = 1; off < 256; off <<= 1) {
        int v = (tid >= off) ? s[tid - off] : 0;
        __syncthreads();
        s[tid] += v;
        __syncthreads();
    }
    int texcl = s[tid] - tsum;
    if (base + 0 < n) out[base + 0] = texcl;
    if (base + 1 < n) out[base + 1] = texcl + a0;
    if (base + 2 < n) out[base + 2] = texcl + a0 + a1;
    if (base + 3 < n) out[base + 3] = texcl + a0 + a1 + a2;
    if (tid == 255) bsum[blockIdx.x] = s[255];
}

// stage 2
__global__ __launch_bounds__(256) void scan_bsums(int* __restrict__ bsum, int nb) {
    __shared__ int s[256];
    __shared__ int carry_s;
    int tid = threadIdx.x;
    if (tid == 0) carry_s = 0;
    __syncthreads();
    for (int base = 0; base < nb; base += 256) {
        int v = (base + tid < nb) ? bsum[base + tid] : 0;
        int orig = v;
        s[tid] = v;
        __syncthreads();
        for (int off = 1; off < 256; off <<= 1) {
            int u = (tid >= off) ? s[tid - off] : 0;
            __syncthreads();
            s[tid] += u;
            __syncthreads();
        }
        int carry = carry_s;
        int excl = s[tid] - orig + carry;
        if (base + tid < nb) bsum[base + tid] = excl;
        int tot = s[255];
        __syncthreads();
        if (tid == 0) carry_s = carry + tot;
        __syncthreads();
    }
}

// stage 3
__global__ void scan_add(int* __restrict__ rowptr, const int* __restrict__ bscan, int n) {
    int t = blockIdx.x * blockDim.x + threadIdx.x;
    if (t < n) rowptr[t] += bscan[t >> 10];
}

// atomic-free CSR placement
__global__ void scatter_pairs(const int* __restrict__ src, const int* __restrict__ dst,
                              const float* __restrict__ ew, const int* __restrict__ rowptr,
                              const int* __restrict__ rank, int2* __restrict__ pairs, int E) {
    int e = blockIdx.x * blockDim.x + threadIdx.x;
    if (e >= E) return;
    int d = dst[e];
    int p = rowptr[d] + rank[e];
    pairs[p] = make_int2(src[e], __float_as_int(ew[e]));
}

// degree from segment sum of sorted ew; dinv = 1/sqrt(deg+1)
__global__ void deg_dinv_kernel(const int2* __restrict__ pairs, const int* __restrict__ rowptr,
                                float* __restrict__ dinv, int n) {
    int i = blockIdx.x * blockDim.x + threadIdx.x;
    if (i >= n) return;
    int beg = rowptr[i], end = rowptr[i + 1];
    float s = 0.f;
    for (int j = beg; j < end; j++) s += __int_as_float(pairs[j].y);
    dinv[i] = 1.0f / sqrtf(s + 1.0f);
}

// w' = dinv[src] * ew
__global__ void norm_kernel(int2* __restrict__ pairs, const float* __restrict__ dinv, int E) {
    int j = blockIdx.x * blockDim.x + threadIdx.x;
    if (j >= E) return;
    int2 pr = pairs[j];
    pairs[j].y = __float_as_int(__int_as_float(pr.y) * dinv[pr.x]);
}

// ---------------- FUSED layer-1 gather + ReLU + matvec h1@W2 ----------------
// Block = 8 nodes x 32 threads. Phase 1: 8-deep CSR gather -> h1 (regs) -> LDS.
// Phase 2: z[node][64] = h1[node][128] @ W2, W2 staged in 8KB chunks.
// Buries gemm_rt64's VALU work in the gather's idle issue slots; writes only h2' (25.6MB).
__global__ __launch_bounds__(256) void gather_mv_kernel(const float* __restrict__ H,
                                                        const int* __restrict__ rowptr,
                                                        const int2* __restrict__ pairs,
                                                        const float* __restrict__ dinv,
                                                        const float* __restrict__ bias,
                                                        const float* __restrict__ W2,
                                                        float* __restrict__ Z, int n) {
    __shared__ float h1s[8 * 128];   // 4 KB
    __shared__ float w2s[32 * 64];   // 8 KB chunk of W2
    const int t = threadIdx.x;
    const int nl = t >> 5;           // node-local 0..7
    const int c4 = t & 31;           // float4 index within 128-ch row
    const int node = blockIdx.x * 8 + nl;
    const float4* H4 = (const float4*)H;

    float4 a0 = make_float4(0.f, 0.f, 0.f, 0.f);
    float di = 0.f;
    if (node < n) {
        int beg = rowptr[node], end = rowptr[node + 1];
        di = dinv[node];
        float4 hv = H4[(size_t)node * 32 + c4];
        a0.x = hv.x * di; a0.y = hv.y * di; a0.z = hv.z * di; a0.w = hv.w * di;
        float4 a1 = make_float4(0.f, 0.f, 0.f, 0.f);
        float4 a2 = make_float4(0.f, 0.f, 0.f, 0.f);
        float4 a3 = make_float4(0.f, 0.f, 0.f, 0.f);
        int j = beg;
        for (; j + 8 <= end; j += 8) {
            int2 p0 = pairs[j + 0], p1 = pairs[j + 1], p2 = pairs[j + 2], p3 = pairs[j + 3];
            int2 p4 = pairs[j + 4], p5 = pairs[j + 5], p6 = pairs[j + 6], p7 = pairs[j + 7];
            float4 v0 = H4[(size_t)p0.x * 32 + c4];
            float4 v1 = H4[(size_t)p1.x * 32 + c4];
            float4 v2 = H4[(size_t)p2.x * 32 + c4];
            float4 v3 = H4[(size_t)p3.x * 32 + c4];
            float4 v4 = H4[(size_t)p4.x * 32 + c4];
            float4 v5 = H4[(size_t)p5.x * 32 + c4];
            float4 v6 = H4[(size_t)p6.x * 32 + c4];
            float4 v7 = H4[(size_t)p7.x * 32 + c4];
            float w0 = __int_as_float(p0.y), w1 = __int_as_float(p1.y);
            float w2 = __int_as_float(p2.y), w3 = __int_as_float(p3.y);
            float w4 = __int_as_float(p4.y), w5 = __int_as_float(p5.y);
            float w6 = __int_as_float(p6.y), w7 = __int_as_float(p7.y);
            a0.x += v0.x * w0; a0.y += v0.y * w0; a0.z += v0.z * w0; a0.w += v0.w * w0;
            a1.x += v1.x * w1; a1.y += v1.y * w1; a1.z += v1.z * w1; a1.w += v1.w * w1;
            a2.x += v2.x * w2; a2.y += v2.y * w2; a2.z += v2.z * w2; a2.w += v2.w * w2;
            a3.x += v3.x * w3; a3.y += v3.y * w3; a3.z += v3.z * w3; a3.w += v3.w * w3;
            a0.x += v4.x * w4; a0.y += v4.y * w4; a0.z += v4.z * w4; a0.w += v4.w * w4;
            a1.x += v5.x * w5; a1.y += v5.y * w5; a1.z += v5.z * w5; a1.w += v5.w * w5;
            a2.x += v6.x * w6; a2.y += v6.y * w6; a2.z += v6.z * w6; a2.w += v6.w * w6;
            a3.x += v7.x * w7; a3.y += v7.y * w7; a3.z += v7.z * w7; a3.w += v7.w * w7;
        }
        if (j + 4 <= end) {
            int2 p0 = pairs[j + 0], p1 = pairs[j + 1], p2 = pairs[j + 2], p3 = pairs[j + 3];
            float4 v0 = H4[(size_t)p0.x * 32 + c4];
            float4 v1 = H4[(size_t)p1.x * 32 + c4];
            float4 v2 = H4[(size_t)p2.x * 32 + c4];
            float4 v3 = H4[(size_t)p3.x * 32 + c4];
            float w0 = __int_as_float(p0.y), w1 = __int_as_float(p1.y);
            float w2 = __int_as_float(p2.y), w3 = __int_as_float(p3.y);
            a0.x += v0.x * w0; a0.y += v0.y * w0; a0.z += v0.z * w0; a0.w += v0.w * w0;
            a1.x += v1.x * w1; a1.y += v1.y * w1; a1.z += v1.z * w1; a1.w += v1.w * w1;
            a2.x += v2.x * w2; a2.y += v2.y * w2; a2.z += v2.z * w2; a2.w += v2.w * w2;
            a3.x += v3.x * w3; a3.y += v3.y * w3; a3.z += v3.z * w3; a3.w += v3.w * w3;
            j += 4;
        }
        for (; j < end; j++) {
            int2 pr = pairs[j];
            float w = __int_as_float(pr.y);
            float4 v = H4[(size_t)pr.x * 32 + c4];
            a0.x += v.x * w; a0.y += v.y * w; a0.z += v.z * w; a0.w += v.w * w;
        }
        float4 bb = ((const float4*)bias)[c4];
        a0.x = fmaxf(((a0.x + a1.x) + (a2.x + a3.x)) * di + bb.x, 0.f);
        a0.y = fmaxf(((a0.y + a1.y) + (a2.y + a3.y)) * di + bb.y, 0.f);
        a0.z = fmaxf(((a0.z + a1.z) + (a2.z + a3.z)) * di + bb.z, 0.f);
        a0.w = fmaxf(((a0.w + a1.w) + (a2.w + a3.w)) * di + bb.w, 0.f);
    }
    *(float4*)&h1s[nl * 128 + c4 * 4] = a0;   // h1 (relu'd); garbage rows unused

    // ---- phase 2: z[node][2 cols per thread] = h1 @ W2, chunked over k ----
    float z0 = 0.f, z1 = 0.f;
    for (int kc = 0; kc < 128; kc += 32) {
        __syncthreads();
        {   // stage W2[kc..kc+32) x 64 : 2048 floats = 512 float4
            const float4* W2g = (const float4*)(W2 + kc * 64);
            float4* w2s4 = (float4*)w2s;
            for (int f = t; f < 512; f += 256) w2s4[f] = W2g[f];
        }
        __syncthreads();
        const float* hrow = &h1s[nl * 128 + kc];
        const float2* w2c = (const float2*)w2s;   // [32][32] float2
#pragma unroll 8
        for (int k = 0; k < 32; k++) {
            float hk = hrow[k];                   // LDS broadcast within node group
            float2 w = w2c[k * 32 + c4];
            z0 += hk * w.x;
            z1 += hk * w.y;
        }
    }
    if (node < n) *(float2*)&Z[(size_t)node * 64 + c4 * 2] = make_float2(z0, z1);
}

// ---------------- CSR segmented gather-reduce (layer 2, C=64) ----------------
template<int C, bool RELU>
__global__ __launch_bounds__(256) void gather_reduce(const float* __restrict__ H,
                                                     const int* __restrict__ rowptr,
                                                     const int2* __restrict__ pairs,
                                                     const float* __restrict__ dinv,
                                                     const float* __restrict__ bias,
                                                     float* __restrict__ out, int n) {
    constexpr int TPN = C / 4;
    int t = blockIdx.x * blockDim.x + threadIdx.x;
    int node = t / TPN;
    int c4 = t % TPN;
    if (node >= n) return;
    const float4* H4 = (const float4*)H;
    int beg = rowptr[node], end = rowptr[node + 1];
    float di = dinv[node];
    float4 hv = H4[(size_t)node * TPN + c4];
    float4 bb = ((const float4*)bias)[c4];
    float4 a0, a1, a2, a3;
    a0.x = hv.x * di; a0.y = hv.y * di; a0.z = hv.z * di; a0.w = hv.w * di;
    a1 = make_float4(0.f, 0.f, 0.f, 0.f);
    a2 = make_float4(0.f, 0.f, 0.f, 0.f);
    a3 = make_float4(0.f, 0.f, 0.f, 0.f);
    int j = beg;
    for (; j + 8 <= end; j += 8) {
        int2 p0 = pairs[j + 0], p1 = pairs[j + 1], p2 = pairs[j + 2], p3 = pairs[j + 3];
        int2 p4 = pairs[j + 4], p5 = pairs[j + 5], p6 = pairs[j + 6], p7 = pairs[j + 7];
        float4 v0 = H4[(size_t)p0.x * TPN + c4];
        float4 v1 = H4[(size_t)p1.x * TPN + c4];
        float4 v2 = H4[(size_t)p2.x * TPN + c4];
        float4 v3 = H4[(size_t)p3.x * TPN + c4];
        float4 v4 = H4[(size_t)p4.x * TPN + c4];
        float4 v5 = H4[(size_t)p5.x * TPN + c4];
        float4 v6 = H4[(size_t)p6.x * TPN + c4];
        float4 v7 = H4[(size_t)p7.x * TPN + c4];
        float w0 = __int_as_float(p0.y), w1 = __int_as_float(p1.y);
        float w2 = __int_as_float(p2.y), w3 = __int_as_float(p3.y);
        float w4 = __int_as_float(p4.y), w5 = __int_as_float(p5.y);
        float w6 = __int_as_float(p6.y), w7 = __int_as_float(p7.y);
        a0.x += v0.x * w0; a0.y += v0.y * w0; a0.z += v0.z * w0; a0.w += v0.w * w0;
        a1.x += v1.x * w1; a1.y += v1.y * w1; a1.z += v1.z * w1; a1.w += v1.w * w1;
        a2.x += v2.x * w2; a2.y += v2.y * w2; a2.z += v2.z * w2; a2.w += v2.w * w2;
        a3.x += v3.x * w3; a3.y += v3.y * w3; a3.z += v3.z * w3; a3.w += v3.w * w3;
        a0.x += v4.x * w4; a0.y += v4.y * w4; a0.z += v4.z * w4; a0.w += v4.w * w4;
        a1.x += v5.x * w5; a1.y += v5.y * w5; a1.z += v5.z * w5; a1.w += v5.w * w5;
        a2.x += v6.x * w6; a2.y += v6.y * w6; a2.z += v6.z * w6; a2.w += v6.w * w6;
        a3.x += v7.x * w7; a3.y += v7.y * w7; a3.z += v7.z * w7; a3.w += v7.w * w7;
    }
    if (j + 4 <= end) {
        int2 p0 = pairs[j + 0], p1 = pairs[j + 1], p2 = pairs[j + 2], p3 = pairs[j + 3];
        float4 v0 = H4[(size_t)p0.x * TPN + c4];
        float4 v1 = H4[(size_t)p1.x * TPN + c4];
        float4 v2 = H4[(size_t)p2.x * TPN + c4];
        float4 v3 = H4[(size_t)p3.x * TPN + c4];
        float w0 = __int_as_float(p0.y), w1 = __int_as_float(p1.y);
        float w2 = __int_as_float(p2.y), w3 = __int_as_float(p3.y);
        a0.x += v0.x * w0; a0.y += v0.y * w0; a0.z += v0.z * w0; a0.w += v0.w * w0;
        a1.x += v1.x * w1; a1.y += v1.y * w1; a1.z += v1.z * w1; a1.w += v1.w * w1;
        a2.x += v2.x * w2; a2.y += v2.y * w2; a2.z += v2.z * w2; a2.w += v2.w * w2;
        a3.x += v3.x * w3; a3.y += v3.y * w3; a3.z += v3.z * w3; a3.w += v3.w * w3;
        j += 4;
    }
    for (; j < end; j++) {
        int2 pr = pairs[j];
        float w = __int_as_float(pr.y);
        float4 v = H4[(size_t)pr.x * TPN + c4];
        a0.x += v.x * w; a0.y += v.y * w; a0.z += v.z * w; a0.w += v.w * w;
    }
    float4 acc;
    acc.x = ((a0.x + a1.x) + (a2.x + a3.x)) * di + bb.x;
    acc.y = ((a0.y + a1.y) + (a2.y + a3.y)) * di + bb.y;
    acc.z = ((a0.z + a1.z) + (a2.z + a3.z)) * di + bb.z;
    acc.w = ((a0.w + a1.w) + (a2.w + a3.w)) * di + bb.w;
    if (RELU) {
        acc.x = fmaxf(acc.x, 0.f);
        acc.y = fmaxf(acc.y, 0.f);
        acc.z = fmaxf(acc.z, 0.f);
        acc.w = fmaxf(acc.w, 0.f);
    }
    *(float4*)&out[(size_t)node * C + c4 * 4] = acc;
}

// ---------------- decode ----------------
__global__ void decode_kernel(const float* __restrict__ Z, const int* __restrict__ ea,
                              const int* __restrict__ eb, float* __restrict__ out, int L) {
    int t = blockIdx.x * blockDim.x + threadIdx.x;
    int e = t >> 4;
    int c = (t & 15) << 2;
    if (e >= L) return;
    float4 za = *(const float4*)&Z[(size_t)ea[e] * 64 + c];
    float4 zb = *(const float4*)&Z[(size_t)eb[e] * 64 + c];
    float p = za.x * zb.x + za.y * zb.y + za.z * zb.z + za.w * zb.w;
    p += __shfl_xor(p, 1);
    p += __shfl_xor(p, 2);
    p += __shfl_xor(p, 4);
    p += __shfl_xor(p, 8);
    if ((t & 15) == 0) out[e] = p;
}

extern "C" void kernel_launch(void* const* d_in, const int* in_sizes, int n_in,
                              void* d_out, int out_size, void* d_ws, size_t ws_size,
                              hipStream_t stream) {
    const float* x   = (const float*)d_in[0];
    const int*   ei  = (const int*)d_in[1];   // [2,E] flat: src = ei, dst = ei+E
    const float* ew  = (const float*)d_in[2];
    const int*   eli = (const int*)d_in[3];   // [2,L] flat
    const float* W1  = (const float*)d_in[4];
    const float* b1  = (const float*)d_in[5];
    const float* W2  = (const float*)d_in[6];
    const float* b2  = (const float*)d_in[7];
    float* out = (float*)d_out;

    const int N = in_sizes[0] / 128;
    const int E = in_sizes[2];
    const int L = in_sizes[3] / 2;
    const int NP = ((N + 255) / 256) * 256;

    float* ws     = (float*)d_ws;
    float* dinv   = ws;                                  // NP
    int*   cnt    = (int*)(ws + NP);                     // NP (needs N+1)
    int*   rowptr = cnt + NP;                            // NP (needs N+1)
    int*   bsum   = rowptr + NP;                         // 1024
    int*   rank   = bsum + 1024;                         // E
    int2*  pairs  = (int2*)(rank + E);                   // E int2
    float* A      = (float*)(pairs + E);                 // NP*128  (h = x@W1; later z)
    float* B      = A + (size_t)NP * 128;                // NP*128  (h2' = h1@W2)

    const int n1 = N + 1;
    const int nb = (n1 + 1023) / 1024;

    hipMemsetAsync(cnt, 0, (size_t)n1 * 4, stream);

    // stagger-fused: layer-1 GEMM tiles + histogram/rank slices
    const int Gg = (N + 63) / 64;
    gemm128_hist_kernel<<<Gg, 256, 0, stream>>>(x, W1, A, N, ei + E, cnt, rank, E);

    // CSR finish
    scan_block<<<nb, 256, 0, stream>>>(cnt, rowptr, bsum, n1);
    scan_bsums<<<1, 256, 0, stream>>>(bsum, nb);
    scan_add<<<(n1 + 255) / 256, 256, 0, stream>>>(rowptr, bsum, n1);
    scatter_pairs<<<(E + 255) / 256, 256, 0, stream>>>(ei, ei + E, ew, rowptr, rank, pairs, E);
    deg_dinv_kernel<<<(N + 255) / 256, 256, 0, stream>>>(pairs, rowptr, dinv, N);
    norm_kernel<<<(E + 255) / 256, 256, 0, stream>>>(pairs, dinv, E);

    // FUSED: layer-1 aggregate + ReLU + h1@W2  ->  B holds h2' [N,64]
    gather_mv_kernel<<<(N + 7) / 8, 256, 0, stream>>>(A, rowptr, pairs, dinv, b1, W2, B, N);

    // layer-2 aggregate: z = Â h2' + b2  ->  A (first N*64)
    gather_reduce<64, false><<<(N * 16 + 255) / 256, 256, 0, stream>>>(B, rowptr, pairs, dinv, b2, A, N);

    // decode
    decode_kernel<<<(L * 16 + 255) / 256, 256, 0, stream>>>(A, eli, eli + L, out, L);
}

// Round 11
// 484.177 us; speedup vs baseline: 1.1579x; 1.0160x over previous
//
#include <hip/hip_runtime.h>
#include <math.h>

// ---------------- STAGGER-FUSED: every block does ONE GEMM tile AND one hist slice ----------------
__global__ __launch_bounds__(256) void gemm128_hist_kernel(
        const float* __restrict__ X, const float* __restrict__ W, float* __restrict__ Y, int n,
        const int* __restrict__ dst, int* __restrict__ cnt, int* __restrict__ rank, int E) {
    constexpr int CG  = 32;
    constexpr int RG  = 8;
    constexpr int M   = 64;
    constexpr int RT  = 8;
    constexpr int KC  = 32;
    constexpr int LDX = 132;
    __shared__ float  Xl[M * LDX];      // 33792 B
    __shared__ float4 Wl[KC * CG];      // 16384 B

    const int bid = blockIdx.x;
    const int t = threadIdx.x;
    const int EPB = (E + (int)gridDim.x - 1) / (int)gridDim.x;
    const int eBeg = bid * EPB;
    const int eEnd = min(eBeg + EPB, E);

    if ((bid & 1) == 0) {
        for (int e = eBeg + t; e < eEnd; e += 256)
            rank[e] = atomicAdd(&cnt[dst[e]], 1);
    }

    int row0 = bid * M;
    {
        const float4* Xg = (const float4*)X;
        for (int f = t; f < M * 32; f += 256) {
            int r = f >> 5, c4 = f & 31;
            int gr = row0 + r;
            float4 v = make_float4(0.f, 0.f, 0.f, 0.f);
            if (gr < n) v = Xg[(size_t)gr * 32 + c4];
            *(float4*)&Xl[r * LDX + c4 * 4] = v;
        }
    }

    int cg = t % CG;
    int r0 = (t / CG) * RT;

    float4 acc[RT];
#pragma unroll
    for (int r = 0; r < RT; r++) acc[r] = make_float4(0.f, 0.f, 0.f, 0.f);

    const float4* Wg = (const float4*)W;
    for (int kc = 0; kc < 128; kc += KC) {
        __syncthreads();
        for (int f = t; f < KC * CG; f += 256)
            Wl[f] = Wg[(size_t)kc * CG + f];
        __syncthreads();
#pragma unroll 4
        for (int k = 0; k < KC; k += 4) {
            float4 b0 = Wl[(k + 0) * CG + cg];
            float4 b1 = Wl[(k + 1) * CG + cg];
            float4 b2 = Wl[(k + 2) * CG + cg];
            float4 b3 = Wl[(k + 3) * CG + cg];
#pragma unroll
            for (int r = 0; r < RT; r++) {
                float4 a = *(float4*)&Xl[(r0 + r) * LDX + kc + k];
                acc[r].x += a.x * b0.x + a.y * b1.x + a.z * b2.x + a.w * b3.x;
                acc[r].y += a.x * b0.y + a.y * b1.y + a.z * b2.y + a.w * b3.y;
                acc[r].z += a.x * b0.z + a.y * b1.z + a.z * b2.z + a.w * b3.z;
                acc[r].w += a.x * b0.w + a.y * b1.w + a.z * b2.w + a.w * b3.w;
            }
        }
    }

#pragma unroll
    for (int r = 0; r < RT; r++) {
        int gr = row0 + r0 + r;
        if (gr < n) *(float4*)&Y[(size_t)gr * 128 + cg * 4] = acc[r];
    }

    if (bid & 1) {
        for (int e = eBeg + t; e < eEnd; e += 256)
            rank[e] = atomicAdd(&cnt[dst[e]], 1);
    }
}

// exclusive scan, stage 1
__global__ __launch_bounds__(256) void scan_block(const int* __restrict__ in, int* __restrict__ out,
                                                  int* __restrict__ bsum, int n) {
    __shared__ int s[256];
    int tid = threadIdx.x;
    int base = blockIdx.x * 1024 + tid * 4;
    int a0 = (base + 0 < n) ? in[base + 0] : 0;
    int a1 = (base + 1 < n) ? in[base + 1] : 0;
    int a2 = (base + 2 < n) ? in[base + 2] : 0;
    int a3 = (base + 3 < n) ? in[base + 3] : 0;
    int tsum = a0 + a1 + a2 + a3;
    s[tid] = tsum;
    __syncthreads();
    for (int off = 1; off < 256; off <<= 1) {
        int v = (tid >= off) ? s[tid - off] : 0;
        __syncthreads();
        s[tid] += v;
        __syncthreads();
    }
    int texcl = s[tid] - tsum;
    if (base + 0 < n) out[base + 0] = texcl;
    if (base + 1 < n) out[base + 1] = texcl + a0;
    if (base + 2 < n) out[base + 2] = texcl + a0 + a1;
    if (base + 3 < n) out[base + 3] = texcl + a0 + a1 + a2;
    if (tid == 255) bsum[blockIdx.x] = s[255];
}

// stage 2
__global__ __launch_bounds__(256) void scan_bsums(int* __restrict__ bsum, int nb) {
    __shared__ int s[256];
    __shared__ int carry_s;
    int tid = threadIdx.x;
    if (tid == 0) carry_s = 0;
    __syncthreads();
    for (int base = 0; base < nb; base += 256) {
        int v = (base + tid < nb) ? bsum[base + tid] : 0;
        int orig = v;
        s[tid] = v;
        __syncthreads();
        for (int off = 1; off < 256; off <<= 1) {
            int u = (tid >= off) ? s[tid - off] : 0;
            __syncthreads();
            s[tid] += u;
            __syncthreads();
        }
        int carry = carry_s;
        int excl = s[tid] - orig + carry;
        if (base + tid < nb) bsum[base + tid] = excl;
        int tot = s[255];
        __syncthreads();
        if (tid == 0) carry_s = carry + tot;
        __syncthreads();
    }
}

// stage 3
__global__ void scan_add(int* __restrict__ rowptr, const int* __restrict__ bscan, int n) {
    int t = blockIdx.x * blockDim.x + threadIdx.x;
    if (t < n) rowptr[t] += bscan[t >> 10];
}

// atomic-free CSR placement: pairs hold (src, RAW ew); dinv[src] applied in gather loops
__global__ void scatter_pairs(const int* __restrict__ src, const int* __restrict__ dst,
                              const float* __restrict__ ew, const int* __restrict__ rowptr,
                              const int* __restrict__ rank, int2* __restrict__ pairs, int E) {
    int e = blockIdx.x * blockDim.x + threadIdx.x;
    if (e >= E) return;
    int d = dst[e];
    int p = rowptr[d] + rank[e];
    pairs[p] = make_int2(src[e], __float_as_int(ew[e]));
}

// degree from segment sum of sorted RAW ew; dinv = 1/sqrt(deg+1)
__global__ void deg_dinv_kernel(const int2* __restrict__ pairs, const int* __restrict__ rowptr,
                                float* __restrict__ dinv, int n) {
    int i = blockIdx.x * blockDim.x + threadIdx.x;
    if (i >= n) return;
    int beg = rowptr[i], end = rowptr[i + 1];
    float s = 0.f;
    for (int j = beg; j < end; j++) s += __int_as_float(pairs[j].y);
    dinv[i] = 1.0f / sqrtf(s + 1.0f);
}

// ---------------- FUSED layer-1 gather + ReLU + matvec h1@W2 ----------------
// W2 (32 KB) staged ONCE at block start; single __syncthreads between gather and matvec.
// LDS 36 KB -> 4 blocks/CU = 16 waves (~ current measured occupancy), 7 fewer barriers.
__global__ __launch_bounds__(256) void gather_mv_kernel(const float* __restrict__ H,
                                                        const int* __restrict__ rowptr,
                                                        const int2* __restrict__ pairs,
                                                        const float* __restrict__ dinv,
                                                        const float* __restrict__ bias,
                                                        const float* __restrict__ W2,
                                                        float* __restrict__ Z, int n) {
    __shared__ float h1s[8 * 128];     // 4 KB
    __shared__ float w2s[128 * 64];    // 32 KB, full W2
    const int t = threadIdx.x;
    const int nl = t >> 5;
    const int c4 = t & 31;
    const int node = blockIdx.x * 8 + nl;
    const float4* H4 = (const float4*)H;

    // stage full W2 (coalesced; L2-hot after first blocks)
    {
        const float4* W2g = (const float4*)W2;
        float4* w2s4 = (float4*)w2s;
#pragma unroll
        for (int f = 0; f < 8; f++) w2s4[f * 256 + t] = W2g[f * 256 + t];
    }

    float4 a0 = make_float4(0.f, 0.f, 0.f, 0.f);
    if (node < n) {
        int beg = rowptr[node], end = rowptr[node + 1];
        float di = dinv[node];
        float4 hv = H4[(size_t)node * 32 + c4];
        a0.x = hv.x * di; a0.y = hv.y * di; a0.z = hv.z * di; a0.w = hv.w * di;
        float4 a1 = make_float4(0.f, 0.f, 0.f, 0.f);
        float4 a2 = make_float4(0.f, 0.f, 0.f, 0.f);
        float4 a3 = make_float4(0.f, 0.f, 0.f, 0.f);
        int j = beg;
        for (; j + 8 <= end; j += 8) {
            int2 p0 = pairs[j + 0], p1 = pairs[j + 1], p2 = pairs[j + 2], p3 = pairs[j + 3];
            int2 p4 = pairs[j + 4], p5 = pairs[j + 5], p6 = pairs[j + 6], p7 = pairs[j + 7];
            float4 v0 = H4[(size_t)p0.x * 32 + c4];
            float4 v1 = H4[(size_t)p1.x * 32 + c4];
            float4 v2 = H4[(size_t)p2.x * 32 + c4];
            float4 v3 = H4[(size_t)p3.x * 32 + c4];
            float4 v4 = H4[(size_t)p4.x * 32 + c4];
            float4 v5 = H4[(size_t)p5.x * 32 + c4];
            float4 v6 = H4[(size_t)p6.x * 32 + c4];
            float4 v7 = H4[(size_t)p7.x * 32 + c4];
            float w0 = dinv[p0.x] * __int_as_float(p0.y);
            float w1 = dinv[p1.x] * __int_as_float(p1.y);
            float w2 = dinv[p2.x] * __int_as_float(p2.y);
            float w3 = dinv[p3.x] * __int_as_float(p3.y);
            float w4 = dinv[p4.x] * __int_as_float(p4.y);
            float w5 = dinv[p5.x] * __int_as_float(p5.y);
            float w6 = dinv[p6.x] * __int_as_float(p6.y);
            float w7 = dinv[p7.x] * __int_as_float(p7.y);
            a0.x += v0.x * w0; a0.y += v0.y * w0; a0.z += v0.z * w0; a0.w += v0.w * w0;
            a1.x += v1.x * w1; a1.y += v1.y * w1; a1.z += v1.z * w1; a1.w += v1.w * w1;
            a2.x += v2.x * w2; a2.y += v2.y * w2; a2.z += v2.z * w2; a2.w += v2.w * w2;
            a3.x += v3.x * w3; a3.y += v3.y * w3; a3.z += v3.z * w3; a3.w += v3.w * w3;
            a0.x += v4.x * w4; a0.y += v4.y * w4; a0.z += v4.z * w4; a0.w += v4.w * w4;
            a1.x += v5.x * w5; a1.y += v5.y * w5; a1.z += v5.z * w5; a1.w += v5.w * w5;
            a2.x += v6.x * w6; a2.y += v6.y * w6; a2.z += v6.z * w6; a2.w += v6.w * w6;
            a3.x += v7.x * w7; a3.y += v7.y * w7; a3.z += v7.z * w7; a3.w += v7.w * w7;
        }
        if (j + 4 <= end) {
            int2 p0 = pairs[j + 0], p1 = pairs[j + 1], p2 = pairs[j + 2], p3 = pairs[j + 3];
            float4 v0 = H4[(size_t)p0.x * 32 + c4];
            float4 v1 = H4[(size_t)p1.x * 32 + c4];
            float4 v2 = H4[(size_t)p2.x * 32 + c4];
            float4 v3 = H4[(size_t)p3.x * 32 + c4];
            float w0 = dinv[p0.x] * __int_as_float(p0.y);
            float w1 = dinv[p1.x] * __int_as_float(p1.y);
            float w2 = dinv[p2.x] * __int_as_float(p2.y);
            float w3 = dinv[p3.x] * __int_as_float(p3.y);
            a0.x += v0.x * w0; a0.y += v0.y * w0; a0.z += v0.z * w0; a0.w += v0.w * w0;
            a1.x += v1.x * w1; a1.y += v1.y * w1; a1.z += v1.z * w1; a1.w += v1.w * w1;
            a2.x += v2.x * w2; a2.y += v2.y * w2; a2.z += v2.z * w2; a2.w += v2.w * w2;
            a3.x += v3.x * w3; a3.y += v3.y * w3; a3.z += v3.z * w3; a3.w += v3.w * w3;
            j += 4;
        }
        for (; j < end; j++) {
            int2 pr = pairs[j];
            float w = dinv[pr.x] * __int_as_float(pr.y);
            float4 v = H4[(size_t)pr.x * 32 + c4];
            a0.x += v.x * w; a0.y += v.y * w; a0.z += v.z * w; a0.w += v.w * w;
        }
        float4 bb = ((const float4*)bias)[c4];
        a0.x = fmaxf(((a0.x + a1.x) + (a2.x + a3.x)) * di + bb.x, 0.f);
        a0.y = fmaxf(((a0.y + a1.y) + (a2.y + a3.y)) * di + bb.y, 0.f);
        a0.z = fmaxf(((a0.z + a1.z) + (a2.z + a3.z)) * di + bb.z, 0.f);
        a0.w = fmaxf(((a0.w + a1.w) + (a2.w + a3.w)) * di + bb.w, 0.f);
    }
    *(float4*)&h1s[nl * 128 + c4 * 4] = a0;
    __syncthreads();   // the ONLY barrier: covers w2s staging + h1s

    // matvec: z[node][2c4], z[node][2c4+1]
    float z0 = 0.f, z1 = 0.f;
    const float* hrow = &h1s[nl * 128];
    const float2* w2c = (const float2*)w2s;   // [128][32] float2
#pragma unroll 8
    for (int k = 0; k < 128; k++) {
        float hk = hrow[k];                   // LDS broadcast within node group
        float2 w = w2c[k * 32 + c4];
        z0 += hk * w.x;
        z1 += hk * w.y;
    }
    if (node < n) *(float2*)&Z[(size_t)node * 64 + c4 * 2] = make_float2(z0, z1);
}

// ---------------- CSR segmented gather-reduce (layer 2, C=64), dinv[src] in-loop ----------------
template<int C, bool RELU>
__global__ __launch_bounds__(256) void gather_reduce(const float* __restrict__ H,
                                                     const int* __restrict__ rowptr,
                                                     const int2* __restrict__ pairs,
                                                     const float* __restrict__ dinv,
                                                     const float* __restrict__ bias,
                                                     float* __restrict__ out, int n) {
    constexpr int TPN = C / 4;
    int t = blockIdx.x * blockDim.x + threadIdx.x;
    int node = t / TPN;
    int c4 = t % TPN;
    if (node >= n) return;
    const float4* H4 = (const float4*)H;
    int beg = rowptr[node], end = rowptr[node + 1];
    float di = dinv[node];
    float4 hv = H4[(size_t)node * TPN + c4];
    float4 bb = ((const float4*)bias)[c4];
    float4 a0, a1, a2, a3;
    a0.x = hv.x * di; a0.y = hv.y * di; a0.z = hv.z * di; a0.w = hv.w * di;
    a1 = make_float4(0.f, 0.f, 0.f, 0.f);
    a2 = make_float4(0.f, 0.f, 0.f, 0.f);
    a3 = make_float4(0.f, 0.f, 0.f, 0.f);
    int j = beg;
    for (; j + 8 <= end; j += 8) {
        int2 p0 = pairs[j + 0], p1 = pairs[j + 1], p2 = pairs[j + 2], p3 = pairs[j + 3];
        int2 p4 = pairs[j + 4], p5 = pairs[j + 5], p6 = pairs[j + 6], p7 = pairs[j + 7];
        float4 v0 = H4[(size_t)p0.x * TPN + c4];
        float4 v1 = H4[(size_t)p1.x * TPN + c4];
        float4 v2 = H4[(size_t)p2.x * TPN + c4];
        float4 v3 = H4[(size_t)p3.x * TPN + c4];
        float4 v4 = H4[(size_t)p4.x * TPN + c4];
        float4 v5 = H4[(size_t)p5.x * TPN + c4];
        float4 v6 = H4[(size_t)p6.x * TPN + c4];
        float4 v7 = H4[(size_t)p7.x * TPN + c4];
        float w0 = dinv[p0.x] * __int_as_float(p0.y);
        float w1 = dinv[p1.x] * __int_as_float(p1.y);
        float w2 = dinv[p2.x] * __int_as_float(p2.y);
        float w3 = dinv[p3.x] * __int_as_float(p3.y);
        float w4 = dinv[p4.x] * __int_as_float(p4.y);
        float w5 = dinv[p5.x] * __int_as_float(p5.y);
        float w6 = dinv[p6.x] * __int_as_float(p6.y);
        float w7 = dinv[p7.x] * __int_as_float(p7.y);
        a0.x += v0.x * w0; a0.y += v0.y * w0; a0.z += v0.z * w0; a0.w += v0.w * w0;
        a1.x += v1.x * w1; a1.y += v1.y * w1; a1.z += v1.z * w1; a1.w += v1.w * w1;
        a2.x += v2.x * w2; a2.y += v2.y * w2; a2.z += v2.z * w2; a2.w += v2.w * w2;
        a3.x += v3.x * w3; a3.y += v3.y * w3; a3.z += v3.z * w3; a3.w += v3.w * w3;
        a0.x += v4.x * w4; a0.y += v4.y * w4; a0.z += v4.z * w4; a0.w += v4.w * w4;
        a1.x += v5.x * w5; a1.y += v5.y * w5; a1.z += v5.z * w5; a1.w += v5.w * w5;
        a2.x += v6.x * w6; a2.y += v6.y * w6; a2.z += v6.z * w6; a2.w += v6.w * w6;
        a3.x += v7.x * w7; a3.y += v7.y * w7; a3.z += v7.z * w7; a3.w += v7.w * w7;
    }
    if (j + 4 <= end) {
        int2 p0 = pairs[j + 0], p1 = pairs[j + 1], p2 = pairs[j + 2], p3 = pairs[j + 3];
        float4 v0 = H4[(size_t)p0.x * TPN + c4];
        float4 v1 = H4[(size_t)p1.x * TPN + c4];
        float4 v2 = H4[(size_t)p2.x * TPN + c4];
        float4 v3 = H4[(size_t)p3.x * TPN + c4];
        float w0 = dinv[p0.x] * __int_as_float(p0.y);
        float w1 = dinv[p1.x] * __int_as_float(p1.y);
        float w2 = dinv[p2.x] * __int_as_float(p2.y);
        float w3 = dinv[p3.x] * __int_as_float(p3.y);
        a0.x += v0.x * w0; a0.y += v0.y * w0; a0.z += v0.z * w0; a0.w += v0.w * w0;
        a1.x += v1.x * w1; a1.y += v1.y * w1; a1.z += v1.z * w1; a1.w += v1.w * w1;
        a2.x += v2.x * w2; a2.y += v2.y * w2; a2.z += v2.z * w2; a2.w += v2.w * w2;
        a3.x += v3.x * w3; a3.y += v3.y * w3; a3.z += v3.z * w3; a3.w += v3.w * w3;
        j += 4;
    }
    for (; j < end; j++) {
        int2 pr = pairs[j];
        float w = dinv[pr.x] * __int_as_float(pr.y);
        float4 v = H4[(size_t)pr.x * TPN + c4];
        a0.x += v.x * w; a0.y += v.y * w; a0.z += v.z * w; a0.w += v.w * w;
    }
    float4 acc;
    acc.x = ((a0.x + a1.x) + (a2.x + a3.x)) * di + bb.x;
    acc.y = ((a0.y + a1.y) + (a2.y + a3.y)) * di + bb.y;
    acc.z = ((a0.z + a1.z) + (a2.z + a3.z)) * di + bb.z;
    acc.w = ((a0.w + a1.w) + (a2.w + a3.w)) * di + bb.w;
    if (RELU) {
        acc.x = fmaxf(acc.x, 0.f);
        acc.y = fmaxf(acc.y, 0.f);
        acc.z = fmaxf(acc.z, 0.f);
        acc.w = fmaxf(acc.w, 0.f);
    }
    *(float4*)&out[(size_t)node * C + c4 * 4] = acc;
}

// ---------------- decode ----------------
__global__ void decode_kernel(const float* __restrict__ Z, const int* __restrict__ ea,
                              const int* __restrict__ eb, float* __restrict__ out, int L) {
    int t = blockIdx.x * blockDim.x + threadIdx.x;
    int e = t >> 4;
    int c = (t & 15) << 2;
    if (e >= L) return;
    float4 za = *(const float4*)&Z[(size_t)ea[e] * 64 + c];
    float4 zb = *(const float4*)&Z[(size_t)eb[e] * 64 + c];
    float p = za.x * zb.x + za.y * zb.y + za.z * zb.z + za.w * zb.w;
    p += __shfl_xor(p, 1);
    p += __shfl_xor(p, 2);
    p += __shfl_xor(p, 4);
    p += __shfl_xor(p, 8);
    if ((t & 15) == 0) out[e] = p;
}

extern "C" void kernel_launch(void* const* d_in, const int* in_sizes, int n_in,
                              void* d_out, int out_size, void* d_ws, size_t ws_size,
                              hipStream_t stream) {
    const float* x   = (const float*)d_in[0];
    const int*   ei  = (const int*)d_in[1];   // [2,E] flat: src = ei, dst = ei+E
    const float* ew  = (const float*)d_in[2];
    const int*   eli = (const int*)d_in[3];   // [2,L] flat
    const float* W1  = (const float*)d_in[4];
    const float* b1  = (const float*)d_in[5];
    const float* W2  = (const float*)d_in[6];
    const float* b2  = (const float*)d_in[7];
    float* out = (float*)d_out;

    const int N = in_sizes[0] / 128;
    const int E = in_sizes[2];
    const int L = in_sizes[3] / 2;
    const int NP = ((N + 255) / 256) * 256;

    float* ws     = (float*)d_ws;
    float* dinv   = ws;                                  // NP
    int*   cnt    = (int*)(ws + NP);                     // NP (needs N+1)
    int*   rowptr = cnt + NP;                            // NP (needs N+1)
    int*   bsum   = rowptr + NP;                         // 1024
    int*   rank   = bsum + 1024;                         // E
    int2*  pairs  = (int2*)(rank + E);                   // E int2
    float* A      = (float*)(pairs + E);                 // NP*128  (h = x@W1; later z)
    float* B      = A + (size_t)NP * 128;                // NP*128  (h2' = h1@W2)

    const int n1 = N + 1;
    const int nb = (n1 + 1023) / 1024;

    hipMemsetAsync(cnt, 0, (size_t)n1 * 4, stream);

    // stagger-fused: layer-1 GEMM tiles + histogram/rank slices
    const int Gg = (N + 63) / 64;
    gemm128_hist_kernel<<<Gg, 256, 0, stream>>>(x, W1, A, N, ei + E, cnt, rank, E);

    // CSR finish (pairs keep raw ew; dinv[src] applied in gather loops)
    scan_block<<<nb, 256, 0, stream>>>(cnt, rowptr, bsum, n1);
    scan_bsums<<<1, 256, 0, stream>>>(bsum, nb);
    scan_add<<<(n1 + 255) / 256, 256, 0, stream>>>(rowptr, bsum, n1);
    scatter_pairs<<<(E + 255) / 256, 256, 0, stream>>>(ei, ei + E, ew, rowptr, rank, pairs, E);
    deg_dinv_kernel<<<(N + 255) / 256, 256, 0, stream>>>(pairs, rowptr, dinv, N);

    // FUSED: layer-1 aggregate + ReLU + h1@W2  ->  B holds h2' [N,64]
    gather_mv_kernel<<<(N + 7) / 8, 256, 0, stream>>>(A, rowptr, pairs, dinv, b1, W2, B, N);

    // layer-2 aggregate: z = Â h2' + b2  ->  A (first N*64)
    gather_reduce<64, false><<<(N * 16 + 255) / 256, 256, 0, stream>>>(B, rowptr, pairs, dinv, b2, A, N);

    // decode
    decode_kernel<<<(L * 16 + 255) / 256, 256, 0, stream>>>(A, eli, eli + L, out, L);
}